// Round 5
// baseline (403.540 us; speedup 1.0000x reference)
//
#include <hip/hip_runtime.h>
#include <cstdint>
#include <cstddef>

// ============================================================================
// ProposedConv hypergraph dual-attention (round 5):
//  - big GEMM's H-part (89% of its FLOPs) replaced by sparse gather-sum:
//    G2h[i][e] = rsInv[i] * sum_{n in e} expA[i][n] via per-edge node lists
//    (k_sparse: 512 blocks x 8 rows, node-major LDS stride 24B, b64 gathers)
//  - k_sparse also computes expA in-block (exprows kernel deleted) + rsInv
//  - G1 = expA @ Whg (unscaled f32) co-launched with edge_softmax; rsInv
//    applied in C1's fused combine epilogue
//  - HbT (16 MB zero + scatter + GEMM staging) removed entirely
//  - hn2T: split-K4 + f32 atomics (512 blocks) + tiny cast
// ============================================================================

#define DI __device__ __forceinline__
typedef unsigned short u16;
typedef unsigned int   u32;
typedef __bf16 bf16x8 __attribute__((ext_vector_type(8)));
typedef float  f32x4  __attribute__((ext_vector_type(4)));
typedef u32    u32x4  __attribute__((ext_vector_type(4)));

constexpr int NN  = 4096;   // nodes
constexpr int EE  = 2048;   // hyperedges
constexpr int NNZb = 65536; // incidence nnz

// ---------------- workspace layout (bytes) ----------------
constexpr size_t MB = (size_t)1 << 20;
constexpr size_t OFF_HBITS   = 0;          // u32 [4096][64]
constexpr size_t OFF_HBITST  = 1*MB;       // u32 [2048][128]
constexpr size_t OFF_ABITS   = 2*MB;       // u32 [4096][128]; Edge reuses after k_sparse
constexpr size_t OFF_EDGE    = 2*MB;       //   bf16 [2048][256]
constexpr size_t OFF_WH1     = 4*MB;
constexpr size_t OFF_WH2     = 4*MB + 16384;
constexpr size_t OFF_V       = 4*MB + 32768;
constexpr size_t OFF_RSINV   = 4*MB + 49152;
constexpr size_t OFF_WCAT    = 5*MB;       // bf16 [wgT|w2T|w1T](768x256) + w3b(256x256)
constexpr size_t OFF_XB      = 6*MB;       // bf16 [4096][256]; EdgeT/Hn2T reuse after G0
constexpr size_t OFF_EDGET   = 6*MB;       //   bf16 [256][2048]
constexpr size_t OFF_HN2T    = 7*MB;       //   bf16 [256][2048] ([EdgeT|Hn2T] = C1 B-cat)
constexpr size_t OFF_WHG     = 8*MB;       // bf16 [4096][256]
constexpr size_t OFF_X4ATT   = 10*MB;      // bf16 [4096][256]
constexpr size_t OFF_YB      = 12*MB;      // bf16 [4096][256]
constexpr size_t OFF_XWT     = 14*MB;      // bf16 [256][4096] ([XwT|WhgTa] = edgeT A-cat)
constexpr size_t OFF_WHGTA   = 16*MB;      // bf16 [256][4096]
constexpr size_t OFF_EDGE2T  = 18*MB;      // bf16 [256][2048]
constexpr size_t OFF_GLISTS  = 19*MB;      // u16 [2048][2][64] pass-split edge lists
constexpr size_t OFF_CNT2    = 19*MB + 524288;  // u32 [2048][2]
constexpr size_t OFF_HN2ACC  = 34*MB;      // f32 [256][2048] (atomic; zeroed in prep)
constexpr size_t OFF_EXPA    = 36*MB;      // bf16 [4096][4096]; Att2hn reuses after G1
constexpr size_t OFF_ATT2HN  = 36*MB;      //   bf16 [4096][2048]
constexpr size_t OFF_ATT1T   = 52*MB;      // bf16 [4096][2048]
constexpr size_t OFF_G2H     = 68*MB;      // bf16 [4096][2048]
constexpr size_t OFF_G2HT    = 84*MB;      // bf16 [2048][4096]; Att2hnT reuses
constexpr size_t OFF_ATT2HNT = 84*MB;
constexpr size_t OFF_ATT1    = 100*MB;     // bf16 [2048][4096]; Attn2 reuses after tri
constexpr size_t OFF_ATTN2   = 100*MB;     //   bf16 [4096][2048]
constexpr size_t OFF_G1      = 116*MB;     // f32 [4096][256] (unscaled)
constexpr size_t OFF_C2      = 120*MB;     // f32 [4096][256]

// ---------------- helpers ----------------
DI u16 to_bf(float f) {
  union { float f; u32 u; } x; x.f = f;
  u32 r = x.u + 0x7fffu + ((x.u >> 16) & 1u);
  return (u16)(r >> 16);
}
DI float from_bf(u16 h) { union { u32 u; float f; } x; x.u = (u32)h << 16; return x.f; }
DI float bflo(u32 u) { union { u32 u; float f; } x; x.u = u << 16; return x.f; }
DI float bfhi(u32 u) { union { u32 u; float f; } x; x.u = u & 0xffff0000u; return x.f; }
DI void store_bf4(u16* p, float a, float b, float c, float d) {  // 8B aligned store
  u32 lo = (u32)to_bf(a) | ((u32)to_bf(b) << 16);
  u32 hi = (u32)to_bf(c) | ((u32)to_bf(d) << 16);
  *(u32*)p = lo; *((u32*)p + 1) = hi;
}

DI float wredf(float v) {
  #pragma unroll
  for (int o = 32; o; o >>= 1) v += __shfl_down(v, o);
  return v;
}
DI int wredi(int v) {
  #pragma unroll
  for (int o = 32; o; o >>= 1) v += __shfl_down(v, o);
  return v;
}

typedef __attribute__((address_space(3))) void lds_void;
typedef __attribute__((address_space(1))) void glb_void;
DI void async_load16(const void* g, void* l) {
  __builtin_amdgcn_global_load_lds((glb_void*)(uintptr_t)g,
                                   (lds_void*)(u32)(uintptr_t)l, 16, 0, 0);
}

// ---------------- generic NT bf16 GEMM body (device fn) ----------------
// C[m][n] = sum_{k in [k0,k0+kLen)} A[m][k]*B[n][k]; row stride K.
template <int BM, int BN, class Epi>
DI void gemm_body(const u16* __restrict__ A, const u16* __restrict__ B,
                  int nb, int K, int k0, int kLen, Epi epi, int tile,
                  u16* As, u16* Bs)
{
  constexpr int BK = 64;
  constexpr int WM = BM / 2, WN = BN / 2;
  constexpr int FM = WM / 16, FN = WN / 16;
  constexpr int AI = (BM * 8) / 256, BI = (BN * 8) / 256;

  const int tid = threadIdx.x;
  const int w = tid >> 6, l = tid & 63;
  const int bi = tile / nb, bj = tile - bi * nb;
  const int i0 = bi * BM, j0 = bj * BN;
  const int wm = (w & 1) * WM, wn = (w >> 1) * WN;
  const int quad = l >> 4, m16 = l & 15;

  f32x4 acc[FM][FN] = {};

  for (int kb = k0; kb < k0 + kLen; kb += BK) {
    __syncthreads();
    #pragma unroll
    for (int i = 0; i < AI; ++i) {
      const int ci = (i * 4 + w) * 64 + l;
      const int r = ci >> 3;
      const int lc = (ci & 7) ^ (r & 7);
      async_load16(A + (size_t)(i0 + r) * K + kb + lc * 8, &As[(i * 4 + w) * 512]);
    }
    #pragma unroll
    for (int i = 0; i < BI; ++i) {
      const int ci = (i * 4 + w) * 64 + l;
      const int r = ci >> 3;
      const int lc = (ci & 7) ^ (r & 7);
      async_load16(B + (size_t)(j0 + r) * K + kb + lc * 8, &Bs[(i * 4 + w) * 512]);
    }
    __syncthreads();
    #pragma unroll
    for (int ks = 0; ks < 2; ++ks) {
      bf16x8 af[FM], bfv[FN];
      #pragma unroll
      for (int mi = 0; mi < FM; ++mi) {
        const int row = wm + mi * 16 + m16;
        af[mi] = *(const bf16x8*)&As[row * BK + (((ks * 4 + quad) ^ (row & 7)) * 8)];
      }
      #pragma unroll
      for (int ni = 0; ni < FN; ++ni) {
        const int row = wn + ni * 16 + m16;
        bfv[ni] = *(const bf16x8*)&Bs[row * BK + (((ks * 4 + quad) ^ (row & 7)) * 8)];
      }
      #pragma unroll
      for (int mi = 0; mi < FM; ++mi)
        #pragma unroll
        for (int ni = 0; ni < FN; ++ni)
          acc[mi][ni] = __builtin_amdgcn_mfma_f32_16x16x32_bf16(
              af[mi], bfv[ni], acc[mi][ni], 0, 0, 0);
    }
  }
  // C/D layout: col = lane&15, row = quad*4 + reg
  #pragma unroll
  for (int mi = 0; mi < FM; ++mi)
    #pragma unroll
    for (int ni = 0; ni < FN; ++ni) {
      const int rb = i0 + wm + mi * 16 + quad * 4;
      const int c  = j0 + wn + ni * 16 + m16;
      epi(rb, c, acc[mi][ni]);
    }
}

// 32x32 transpose tile (flat 256 threads); t >= 32*33 u16
DI void t32_tile(const u16* __restrict__ in, u16* __restrict__ out,
                 int R, int C, int bx, int by, u16* t) {
  int tx = threadIdx.x & 31, ty = threadIdx.x >> 5;
  int x0 = bx * 32, y0 = by * 32;
  #pragma unroll
  for (int k = 0; k < 32; k += 8)
    t[(ty + k) * 33 + tx] = in[(size_t)(y0 + ty + k) * C + x0 + tx];
  __syncthreads();
  #pragma unroll
  for (int k = 0; k < 32; k += 8)
    out[(size_t)(x0 + ty + k) * R + y0 + tx] = t[tx * 33 + ty + k];
}

// ---------------- epilogues (rb..rb+3 rows, col c) ----------------
struct EpiG0 {   // x @ [wgT|w2T|w1T]: Whg(+T) | X4att | XwT(+bias)
  u16 *whg, *whgTa, *x4, *xwT; const float* bias;
  DI void operator()(int r, int c, f32x4 v) const {
    if (c < 256) {
      #pragma unroll
      for (int i = 0; i < 4; ++i) whg[(r + i) * 256 + c] = to_bf(v[i]);
      store_bf4(&whgTa[(size_t)c * NN + r], v[0], v[1], v[2], v[3]);
    } else if (c < 512) {
      #pragma unroll
      for (int i = 0; i < 4; ++i) x4[(r + i) * 256 + (c - 256)] = to_bf(v[i]);
    } else {
      float b = bias[c - 512];
      store_bf4(&xwT[(size_t)(c - 512) * NN + r], v[0]+b, v[1]+b, v[2]+b, v[3]+b);
    }
  }
};
struct EpiEdgeT {   // [xwT|WhgTa] x att1: rows<256 -> EdgeT + Edge; else Edge2T
  u16 *edgeT, *edge2T, *edge;
  DI void operator()(int r, int c, f32x4 v) const {
    if (r < 256) {
      #pragma unroll
      for (int i = 0; i < 4; ++i) edgeT[(size_t)(r + i) * EE + c] = to_bf(v[i]);
      store_bf4(&edge[(size_t)c * 256 + r], v[0], v[1], v[2], v[3]);
    } else {
      #pragma unroll
      for (int i = 0; i < 4; ++i) edge2T[(size_t)(r - 256 + i) * EE + c] = to_bf(v[i]);
    }
  }
};
struct EpiCombine { // C1: relu(node) | elu(G1*rsInv + C2 + v) -> d_out
  const float* g1; const float* c2; const float* rsInv; float* out;
  DI void operator()(int r, int c, f32x4 v) const {
    if (c < 256) {
      #pragma unroll
      for (int i = 0; i < 4; ++i) out[(r + i) * 256 + c] = fmaxf(v[i], 0.f);
    } else {
      int d = c - 256;
      #pragma unroll
      for (int i = 0; i < 4; ++i) {
        float s = g1[(r + i) * 256 + d] * rsInv[r + i] + c2[(r + i) * 256 + d] + v[i];
        out[1048576 + (r + i) * 256 + d] = s > 0.f ? s : expm1f(s);
      }
    }
  }
};
struct EpiBf16 { u16* out; int ldn;
  DI void operator()(int r, int c, f32x4 v) const {
    #pragma unroll
    for (int i = 0; i < 4; ++i) out[(size_t)(r + i) * ldn + c] = to_bf(v[i]);
  } };
struct EpiBf16Scale { u16* out; int ldn; float s;
  DI void operator()(int r, int c, f32x4 v) const {
    #pragma unroll
    for (int i = 0; i < 4; ++i) out[(size_t)(r + i) * ldn + c] = to_bf(v[i] * s);
  } };
struct EpiF32 { float* out; int ldn;
  DI void operator()(int r, int c, f32x4 v) const {
    #pragma unroll
    for (int i = 0; i < 4; ++i) out[(size_t)(r + i) * ldn + c] = v[i];
  } };
struct EpiAtomF32 { float* out; int ldn;
  DI void operator()(int r, int c, f32x4 v) const {
    #pragma unroll
    for (int i = 0; i < 4; ++i) atomicAdd(&out[(size_t)(r + i) * ldn + c], v[i]);
  } };

// ---------------- GEMM wrapper with split-K ----------------
template <int BM, int BN, int S, int LB, class Epi>
__global__ __launch_bounds__(256, LB)
void gemm_k(const u16* __restrict__ A, const u16* __restrict__ B,
            int nb, int K, Epi epi) {
  __shared__ __align__(16) u16 smem[(BM + BN) * 64];
  const int tilesPer = gridDim.x / S;
  int t = blockIdx.x;
  const int s = t / tilesPer; t -= s * tilesPer;
  const int kLen = K / S;
  gemm_body<BM, BN>(A, B, nb, K, s * kLen, kLen, epi, t, smem, smem + BM * 64);
}

// ---------------- small kernels ----------------
__global__ void k_prep(const float* wg, const float* w2, const float* w1,
                       const float* w3, const float* x, u16* wcat, u16* xb,
                       char* zbits, char* zhn2) {
  int idx = blockIdx.x * 256 + threadIdx.x;
  if (blockIdx.x < 5120) {            // casts: 1310720 elements
    if (idx < 196608) {
      int blk = idx >> 16, r = idx & 65535;
      int d = r >> 8, kk = r & 255;
      const float* src = blk == 0 ? wg : blk == 1 ? w2 : w1;
      wcat[idx] = to_bf(src[kk * 256 + d]);        // transposed
    } else if (idx < 262144) {
      int r = idx - 196608;
      wcat[196608 + r] = to_bf(w3[r]);             // w3 straight
    } else {
      int r = idx - 262144;
      xb[r] = to_bf(x[r]);
    }
  } else {                            // zero 4 MB bits + 2 MB Hn2Acc (16 B/thread)
    int z = idx - 5120 * 256;
    u32x4 zero = {0, 0, 0, 0};
    if (z < 262144) ((u32x4*)zbits)[z] = zero;
    else            ((u32x4*)zhn2)[z - 262144] = zero;
  }
}

__global__ void k_scatter_diag(const int* __restrict__ hidx, u32* hbits, u32* hbitsT,
                               u32* abits) {
  int k = blockIdx.x * 256 + threadIdx.x;
  if (k < NNZb) {
    int n = hidx[k], e = hidx[NNZb + k];
    atomicOr(&hbits[n * 64 + (e >> 5)], 1u << (e & 31));
    atomicOr(&hbitsT[e * 128 + (n >> 5)], 1u << (n & 31));
  } else {
    int i = k - NNZb;
    if (i < NN) atomicOr(&abits[i * 128 + (i >> 5)], 1u << (i & 31));
  }
}

// blocks [0,1024): rowdots; [1024,3072): clique expansion + edge-list extract
__global__ void k_rowclique(const u16* __restrict__ whg, const u16* __restrict__ x4,
                            const float* __restrict__ ag, const float* __restrict__ wc,
                            float* wh1, float* wh2, float* v,
                            const u32* __restrict__ hbitsT, u32* abits,
                            u16* glists, u32* cnt2) {
  __shared__ int list[512];
  __shared__ int cnt;
  __shared__ u32 c2[2];
  int tid = threadIdx.x;
  if (blockIdx.x < 1024) {
    int wv = tid >> 6, l = tid & 63;
    int row = blockIdx.x * 4 + wv;
    float s1 = 0, s2 = 0, s3 = 0;
    #pragma unroll
    for (int dd = 0; dd < 4; ++dd) {
      int d = l * 4 + dd;
      float a = from_bf(whg[row * 256 + d]);
      s1 += a * ag[d]; s2 += a * ag[256 + d];
      s3 += from_bf(x4[row * 256 + d]) * wc[d];
    }
    s1 = wredf(s1); s2 = wredf(s2); s3 = wredf(s3);
    if (l == 0) { wh1[row] = s1; wh2[row] = s2; v[row] = s3 * (1.0f / 16.0f); }
  } else {
    int e = blockIdx.x - 1024;
    if (tid == 0) cnt = 0;
    if (tid < 2) c2[tid] = 0;
    __syncthreads();
    if (tid < 128) {
      u32 w = hbitsT[e * 128 + tid];
      int p = tid >> 6;            // node >= 2048 ?
      while (w) {
        int b = __ffs(w) - 1;
        int n = tid * 32 + b;
        int q = atomicAdd(&cnt, 1);
        if (q < 512) list[q] = n;
        u32 s = atomicAdd(&c2[p], 1u);
        if (s < 64) glists[(e * 2 + p) * 64 + s] = (u16)n;
        w &= w - 1;
      }
    }
    __syncthreads();
    if (tid < 2) cnt2[e * 2 + tid] = c2[tid] < 64u ? c2[tid] : 64u;
    int c = cnt < 512 ? cnt : 512;
    for (int p = tid; p < c * c; p += 256) {
      int i = list[p / c], j = list[p % c];
      atomicOr(&abits[i * 128 + (j >> 5)], 1u << (j & 31));
    }
  }
}

// 512 blocks x 8 rows: expA compute + rowsum + sparse gather -> G2h/G2hT
__global__ __launch_bounds__(256, 2)
void k_sparse(const u32* __restrict__ abits, const float* __restrict__ wh1,
              const float* __restrict__ wh2, const u16* __restrict__ glists,
              const u32* __restrict__ cnt2, u16* __restrict__ expA,
              float* __restrict__ rsInv, u16* __restrict__ g2h,
              u16* __restrict__ g2hT)
{
  __shared__ u16 lds[2048 * 12];      // node-major, 24 B stride (8 rows + pad)
  __shared__ float sums8[8], rsi[8];
  const int tid = threadIdx.x;
  const int i0 = blockIdx.x * 8;
  const int r = tid & 7, ng = tid >> 3;
  if (tid < 8) sums8[tid] = 0.f;
  float acc[8][8] = {};
  const float wh1r = wh1[i0 + r];
  for (int p = 0; p < 2; ++p) {
    __syncthreads();                  // protect lds from previous gather
    float partial = 0.f;
    for (int it = 0; it < 8; ++it) {
      const int g = ng + 32 * it;     // local node-group 0..255
      const int n0 = p * 2048 + g * 8;
      const u32 m8 = (abits[(size_t)(i0 + r) * 128 + (n0 >> 5)] >> (n0 & 31)) & 0xffu;
      u32 pk[4];
      #pragma unroll
      for (int q = 0; q < 4; ++q) {
        u32 wrd = 0;
        #pragma unroll
        for (int h = 0; h < 2; ++h) {
          const int j = q * 2 + h;
          u16 hb = 0;
          if ((m8 >> j) & 1u) {
            float z = wh1r + wh2[n0 + j];
            float eg = z > 0.f ? z : 0.2f * z;   // LeakyReLU(0.2)
            hb = to_bf(__expf(eg));
            partial += from_bf(hb);
          }
          lds[(g * 8 + j) * 12 + r] = hb;
          wrd |= (u32)hb << (16 * h);
        }
        pk[q] = wrd;
      }
      *(u32x4*)&expA[(size_t)(i0 + r) * 4096 + n0] = u32x4{pk[0], pk[1], pk[2], pk[3]};
    }
    atomicAdd(&sums8[r], partial);
    __syncthreads();
    // gather pass p
    #pragma unroll
    for (int j = 0; j < 8; ++j) {
      const int e = tid + 256 * j;
      const int c = (int)cnt2[e * 2 + p];
      const u16* lst = &glists[(e * 2 + p) * 64];
      for (int k = 0; k < c; ++k) {
        const int ln = (int)lst[k] - p * 2048;
        const u32* lp = (const u32*)&lds[ln * 12];
        u32 a0 = lp[0], a1 = lp[1], a2 = lp[2], a3 = lp[3];
        acc[j][0] += bflo(a0); acc[j][1] += bfhi(a0);
        acc[j][2] += bflo(a1); acc[j][3] += bfhi(a1);
        acc[j][4] += bflo(a2); acc[j][5] += bfhi(a2);
        acc[j][6] += bflo(a3); acc[j][7] += bfhi(a3);
      }
    }
  }
  __syncthreads();
  if (tid < 8) {
    float s = 1.f / sums8[tid];
    rsi[tid] = s; rsInv[i0 + tid] = s;
  }
  __syncthreads();
  #pragma unroll
  for (int j = 0; j < 8; ++j) {
    const int e = tid + 256 * j;
    u32 pk[4];
    #pragma unroll
    for (int q = 0; q < 4; ++q) {
      u16 lo = to_bf(acc[j][2 * q] * rsi[2 * q]);
      u16 hi = to_bf(acc[j][2 * q + 1] * rsi[2 * q + 1]);
      pk[q] = (u32)lo | ((u32)hi << 16);
      g2h[(size_t)(i0 + 2 * q) * EE + e] = lo;
      g2h[(size_t)(i0 + 2 * q + 1) * EE + e] = hi;
    }
    *(u32x4*)&g2hT[(size_t)e * NN + i0] = u32x4{pk[0], pk[1], pk[2], pk[3]};
  }
}

// edge softmax body (shared buffers passed in)
DI void edge_softmax_body(int e, const u16* __restrict__ g2hT,
                          const u32* __restrict__ hbitsT,
                          const float* __restrict__ v, u16* __restrict__ att1,
                          float* evals, u32* hw, float* s1s, float* s2s, int* cs) {
  int tid = threadIdx.x;
  if (tid == 0) { *s1s = 0.f; *s2s = 0.f; *cs = 0; }
  if (tid < 128) hw[tid] = hbitsT[e * 128 + tid];
  __syncthreads();
  float sum1 = 0.f;
  for (int j = tid; j < NN; j += 256) {
    float ev = __expf(from_bf(g2hT[(size_t)e * NN + j]));
    evals[j] = ev; sum1 += ev;
  }
  float sum2 = 0.f; int cnt = 0;
  if (tid < 128) {
    u32 w = hw[tid]; cnt = __popc(w);
    while (w) { int b = __ffs(w) - 1; sum2 += __expf(v[tid * 32 + b]); w &= w - 1; }
  }
  sum1 = wredf(sum1); sum2 = wredf(sum2); cnt = wredi(cnt);
  if ((tid & 63) == 0) { atomicAdd(s1s, sum1); atomicAdd(s2s, sum2); atomicAdd(cs, cnt); }
  __syncthreads();
  float inv1 = 1.0f / *s1s;
  int c = *cs;
  float inv2 = c > 0 ? 1.0f / *s2s : 0.0f;
  float unif = c > 0 ? 0.0f : (1.0f / (float)NN);
  for (int j = tid; j < NN; j += 256) {
    float t = evals[j] * inv1 + unif;
    if ((hw[j >> 5] >> (j & 31)) & 1) t += __expf(v[j]) * inv2;
    att1[(size_t)e * NN + j] = to_bf(t);
  }
}

// dual: G1 GEMM (128 tiles) | edge_softmax (2048 blocks)
__global__ __launch_bounds__(256, 2)
void k_dual_g1(const u16* __restrict__ ExpA, const u16* __restrict__ WhgTa,
               EpiF32 eg,
               const u16* __restrict__ g2hT, const u32* __restrict__ hbitsT,
               const float* __restrict__ v, u16* __restrict__ att1) {
  __shared__ __align__(16) char buf[24576];
  __shared__ float s1s, s2s; __shared__ int cs;
  int b = blockIdx.x;
  if (b < 128) {
    u16* As = (u16*)buf;
    gemm_body<128, 64>(ExpA, WhgTa, 4, NN, 0, NN, eg, b, As, As + 128 * 64);
  } else {
    edge_softmax_body(b - 128, g2hT, hbitsT, v, att1,
                      (float*)buf, (u32*)(buf + 16384), &s1s, &s2s, &cs);
  }
}

// tri: edgeT-cat GEMM (256 tiles) | Yb GEMM (128 tiles) | Att1->Att1T transpose
__global__ __launch_bounds__(256, 2)
void k_tri_edge(const u16* __restrict__ Fcat, const u16* __restrict__ Att1,
                EpiEdgeT e0,
                const u16* __restrict__ X4att, const u16* __restrict__ W3b,
                EpiBf16 e1,
                const u16* __restrict__ tin, u16* __restrict__ tout) {
  __shared__ __align__(16) u16 smem[192 * 64];
  int b = blockIdx.x;
  if (b < 256)      gemm_body<64, 64>(Fcat, Att1, 32, NN, 0, NN, e0, b, smem, smem + 64 * 64);
  else if (b < 384) gemm_body<128, 64>(X4att, W3b, 4, 256, 0, 256, e1, b - 256, smem, smem + 128 * 64);
  else { int t = b - 384; t32_tile(tin, tout, EE, NN, t & 127, t >> 7, smem); }
}

// dual2: C2 GEMM (128 tiles, K=2048) | attn2 GEMM (512 tiles)
__global__ __launch_bounds__(256, 2)
void k_dual_attn2(const u16* __restrict__ Att1T, const u16* __restrict__ Edge2T,
                  EpiF32 e0,
                  const u16* __restrict__ Yb, const u16* __restrict__ Edge,
                  EpiBf16Scale e1) {
  __shared__ __align__(16) u16 smem[256 * 64];
  int b = blockIdx.x;
  if (b < 128) gemm_body<128, 64>(Att1T, Edge2T, 4, EE, 0, EE, e0, b, smem, smem + 128 * 64);
  else         gemm_body<128, 128>(Yb, Edge, 16, 256, 0, 256, e1, b - 128, smem, smem + 128 * 64);
}

__global__ void k_node_softmax(const u16* __restrict__ g2h, const u16* __restrict__ attn2,
                               const u32* __restrict__ hbits, u16* __restrict__ att2hn) {
  int n = blockIdx.x, tid = threadIdx.x;
  __shared__ float ev3[EE], ev4[EE];
  __shared__ u32 hw[64];
  __shared__ float s3s, s4s; __shared__ int cs;
  if (tid == 0) { s3s = 0.f; s4s = 0.f; cs = 0; }
  if (tid < 64) hw[tid] = hbits[n * 64 + tid];
  __syncthreads();
  float s3 = 0.f, s4 = 0.f; int cl = 0;
  for (int e = tid; e < EE; e += 256) {
    float x3 = __expf(from_bf(g2h[(size_t)n * EE + e]));
    ev3[e] = x3; s3 += x3;
    bool m = (hw[e >> 5] >> (e & 31)) & 1;
    float x4 = m ? __expf(from_bf(attn2[(size_t)n * EE + e])) : 0.f;
    ev4[e] = x4; s4 += x4; cl += m;
  }
  s3 = wredf(s3); s4 = wredf(s4); cl = wredi(cl);
  if ((tid & 63) == 0) { atomicAdd(&s3s, s3); atomicAdd(&s4s, s4); atomicAdd(&cs, cl); }
  __syncthreads();
  float inv3 = 1.0f / s3s;
  int c = cs;
  float inv4 = c > 0 ? 1.0f / s4s : 0.0f;
  float unif = c > 0 ? 0.0f : (1.0f / (float)EE);
  for (int e = tid; e < EE; e += 256)
    att2hn[(size_t)n * EE + e] = to_bf(ev3[e] * inv3 + ev4[e] * inv4 + unif);
}

__global__ void k_transpose(const u16* __restrict__ in, u16* __restrict__ out,
                            int R, int C) {
  __shared__ u16 t[32 * 33];
  t32_tile(in, out, R, C, blockIdx.x, blockIdx.y, t);
}

__global__ void k_cast_hn2(const float* __restrict__ acc, u16* __restrict__ hn2T) {
  int idx = blockIdx.x * 256 + threadIdx.x;     // 524288
  hn2T[idx] = to_bf(acc[idx]);
}

// ---------------- launch ----------------
extern "C" void kernel_launch(void* const* d_in, const int* in_sizes, int n_in,
                              void* d_out, int out_size, void* d_ws, size_t ws_size,
                              hipStream_t stream) {
  (void)in_sizes; (void)n_in; (void)out_size; (void)ws_size;
  const float* x    = (const float*)d_in[0];
  const float* w1   = (const float*)d_in[1];
  const float* w2   = (const float*)d_in[2];
  const float* w3   = (const float*)d_in[3];
  const float* wg   = (const float*)d_in[4];
  const float* ag   = (const float*)d_in[5];
  const float* wc   = (const float*)d_in[6];
  const float* bias = (const float*)d_in[7];
  const int*   hidx = (const int*)d_in[8];
  float* out = (float*)d_out;
  char* ws = (char*)d_ws;

  u32* Hbits   = (u32*)(ws + OFF_HBITS);
  u32* HbitsT  = (u32*)(ws + OFF_HBITST);
  u32* Abits   = (u32*)(ws + OFF_ABITS);
  float* Wh1   = (float*)(ws + OFF_WH1);
  float* Wh2   = (float*)(ws + OFF_WH2);
  float* V     = (float*)(ws + OFF_V);
  float* RsInv = (float*)(ws + OFF_RSINV);
  u16* Wcat    = (u16*)(ws + OFF_WCAT);
  u16* W3b     = Wcat + 196608;
  u16* Xb      = (u16*)(ws + OFF_XB);
  u16* Whg     = (u16*)(ws + OFF_WHG);
  u16* X4att   = (u16*)(ws + OFF_X4ATT);
  u16* Yb      = (u16*)(ws + OFF_YB);
  u16* XwT     = (u16*)(ws + OFF_XWT);     // Fcat = [XwT|WhgTa] contiguous
  u16* WhgTa   = (u16*)(ws + OFF_WHGTA);
  u16* Edge2T  = (u16*)(ws + OFF_EDGE2T);
  u16* Glists  = (u16*)(ws + OFF_GLISTS);
  u32* Cnt2    = (u32*)(ws + OFF_CNT2);
  float* Hn2Acc = (float*)(ws + OFF_HN2ACC);
  u16* ExpA    = (u16*)(ws + OFF_EXPA);
  u16* Att2hn  = (u16*)(ws + OFF_ATT2HN);
  u16* Att1T   = (u16*)(ws + OFF_ATT1T);
  u16* G2h     = (u16*)(ws + OFF_G2H);
  u16* G2hT    = (u16*)(ws + OFF_G2HT);
  u16* Att2hnT = (u16*)(ws + OFF_ATT2HNT);
  u16* Att1    = (u16*)(ws + OFF_ATT1);
  u16* Attn2   = (u16*)(ws + OFF_ATTN2);
  float* G1    = (float*)(ws + OFF_G1);
  float* C2    = (float*)(ws + OFF_C2);
  u16* Edge    = (u16*)(ws + OFF_EDGE);
  u16* EdgeT   = (u16*)(ws + OFF_EDGET);   // [EdgeT|Hn2T] = C1 B-cat contiguous
  u16* Hn2T    = (u16*)(ws + OFF_HN2T);

  // 1. casts + zeroing (bits 4 MB, Hn2Acc 2 MB)
  k_prep<<<6656, 256, 0, stream>>>(wg, w2, w1, w3, x, Wcat, Xb,
                                   ws + OFF_HBITS, ws + OFF_HN2ACC);
  // 2. incidence bitsets + A-diagonal
  k_scatter_diag<<<272, 256, 0, stream>>>(hidx, Hbits, HbitsT, Abits);
  // 3. G0: x @ [wgT|w2T|w1T] -> Whg(+T) | X4att | XwT(+bias)
  gemm_k<128, 64, 1, 3><<<384, 256, 0, stream>>>(
      Xb, Wcat, 12, 256, EpiG0{Whg, WhgTa, X4att, XwT, bias});
  // 4. rowdots + clique expansion + pass-split edge lists
  k_rowclique<<<3072, 256, 0, stream>>>(Whg, X4att, ag, wc, Wh1, Wh2, V,
                                        HbitsT, Abits, Glists, Cnt2);
  // 5. sparse: expA + rowsum + G2h/G2hT gather-sum
  k_sparse<<<512, 256, 0, stream>>>(Abits, Wh1, Wh2, Glists, Cnt2,
                                    ExpA, RsInv, G2h, G2hT);
  // 6. dual: G1 = expA @ Whg (unscaled f32) | att1 per edge
  k_dual_g1<<<2176, 256, 0, stream>>>(ExpA, WhgTa, EpiF32{G1, 256},
                                      G2hT, HbitsT, V, Att1);
  // 7. tri: [EdgeT|Edge2T](+Edge) | Yb = X4att@w3^T | Att1->Att1T
  k_tri_edge<<<8576, 256, 0, stream>>>(
      XwT, Att1, EpiEdgeT{EdgeT, Edge2T, Edge},
      X4att, W3b, EpiBf16{Yb, 256},
      Att1, Att1T);
  // 8. dual2: C2 = att1^T @ edge2 | attn2 = Yb @ edge^T / temp
  k_dual_attn2<<<640, 256, 0, stream>>>(
      Att1T, Edge2T, EpiF32{C2, 256},
      Yb, Edge, EpiBf16Scale{Attn2, EE, 1.0f / 16.0f});
  // 9. att2hn per node
  k_node_softmax<<<NN, 256, 0, stream>>>(G2h, Attn2, Hbits, Att2hn);
  // 10. Att2hn -> Att2hnT
  k_transpose<<<dim3(64, 128), 256, 0, stream>>>(Att2hn, Att2hnT, NN, EE);
  // 11. hn2T = Whg^T @ att2hn: split-K4 atomics (512 blocks)
  gemm_k<64, 64, 4, 2><<<512, 256, 0, stream>>>(
      WhgTa, Att2hnT, 32, NN, EpiAtomF32{Hn2Acc, EE});
  // 12. cast Hn2Acc -> Hn2T bf16
  k_cast_hn2<<<2048, 256, 0, stream>>>(Hn2Acc, Hn2T);
  // 13. C1 = att2hn @ [edge|hn2] with fused relu/elu combine -> d_out
  gemm_k<64, 64, 1, 2><<<512, 256, 0, stream>>>(
      Att2hn, EdgeT, 8, EE, EpiCombine{G1, C2, RsInv, out});
}

// Round 6
// 380.321 us; speedup vs baseline: 1.0610x; 1.0610x over previous
//
#include <hip/hip_runtime.h>
#include <cstdint>
#include <cstddef>

// ============================================================================
// ProposedConv hypergraph dual-attention (round 6):
//  - REVERT round-5 sparse gather (LDS bank conflicts + VALU-bound: 90 us vs
//    80 us dense). Dense big GEMM restored.
//  - XCD-aware tile swizzle on big GEMM (xcd=b&7 owns a 3-wide bj stripe):
//    per-XCD B fits 4 MB L2, A streams L3 once -> FETCH 140 -> ~50 MB
//  - same swizzle on tri's EdgeT GEMM (XSW=4)
//  - hn2T: split-K4 f32 atomics (512 blocks, 2/CU) + tiny cast; acc zeroed
//    in prep
// ============================================================================

#define DI __device__ __forceinline__
typedef unsigned short u16;
typedef unsigned int   u32;
typedef __bf16 bf16x8 __attribute__((ext_vector_type(8)));
typedef float  f32x4  __attribute__((ext_vector_type(4)));
typedef u32    u32x4  __attribute__((ext_vector_type(4)));

constexpr int NN  = 4096;   // nodes
constexpr int EE  = 2048;   // hyperedges
constexpr int NNZb = 65536; // incidence nnz

// ---------------- workspace layout (bytes) ----------------
constexpr size_t MB = (size_t)1 << 20;
constexpr size_t OFF_HBITS   = 0;          // u32 [4096][64]
constexpr size_t OFF_HBITST  = 1*MB;       // u32 [2048][128]
constexpr size_t OFF_ABITS   = 2*MB;       // u32 [4096][128]; Edge reuses after exprows
constexpr size_t OFF_EDGE    = 2*MB;       //   bf16 [2048][256]
constexpr size_t OFF_WH1     = 4*MB;
constexpr size_t OFF_WH2     = 4*MB + 16384;
constexpr size_t OFF_V       = 4*MB + 32768;
constexpr size_t OFF_RSINV   = 4*MB + 49152;
constexpr size_t OFF_WCAT    = 5*MB;       // bf16 [wgT|w2T|w1T](768x256) + w3b(256x256)
constexpr size_t OFF_XB      = 6*MB;       // bf16 [4096][256]; EdgeT/Hn2T reuse after G0
constexpr size_t OFF_EDGET   = 6*MB;       //   bf16 [256][2048]
constexpr size_t OFF_HN2T    = 7*MB;       //   bf16 [256][2048] ([EdgeT|Hn2T] = C1 B-cat)
constexpr size_t OFF_WHG     = 8*MB;       // bf16 [4096][256]
constexpr size_t OFF_X4ATT   = 10*MB;      // bf16 [4096][256]
constexpr size_t OFF_YB      = 12*MB;      // bf16 [4096][256]
constexpr size_t OFF_XWT     = 14*MB;      // bf16 [256][4096] ([XwT|WhgTa] = edgeT A-cat)
constexpr size_t OFF_WHGTA   = 16*MB;      // bf16 [256][4096]
constexpr size_t OFF_HBT     = 18*MB;      // bf16 [2048][4096]; Edge2T reuses after bigGEMM
constexpr size_t OFF_EDGE2T  = 18*MB;      //   bf16 [256][2048]
constexpr size_t OFF_WHGTB   = 34*MB;      // bf16 [256][4096] ([HbT|WhgTb] = bigGEMM B-cat)
constexpr size_t OFF_EXPA    = 36*MB;      // bf16 [4096][4096]; dead after bigGEMM
constexpr size_t OFF_ATT1    = 36*MB;      //   bf16 [2048][4096]; dead after tri GEMM
constexpr size_t OFF_ATT2HN  = 36*MB;      //   bf16 [4096][2048]
constexpr size_t OFF_ATT1T   = 52*MB;      // bf16 [4096][2048]
constexpr size_t OFF_G2H     = 68*MB;      // bf16 [4096][2048]
constexpr size_t OFF_G2HT    = 84*MB;      // bf16 [2048][4096]; Att2hnT reuses
constexpr size_t OFF_ATT2HNT = 84*MB;
constexpr size_t OFF_ATTN2   = 100*MB;     // bf16 [4096][2048]
constexpr size_t OFF_G1      = 116*MB;     // f32 [4096][256] (rsInv-scaled, from EpiBig)
constexpr size_t OFF_C2      = 120*MB;     // f32 [4096][256]
constexpr size_t OFF_HN2ACC  = 124*MB;     // f32 [256][2048] (atomic; zeroed in prep)

// ---------------- helpers ----------------
DI u16 to_bf(float f) {
  union { float f; u32 u; } x; x.f = f;
  u32 r = x.u + 0x7fffu + ((x.u >> 16) & 1u);
  return (u16)(r >> 16);
}
DI float from_bf(u16 h) { union { u32 u; float f; } x; x.u = (u32)h << 16; return x.f; }
DI void store_bf4(u16* p, float a, float b, float c, float d) {  // 8B aligned store
  u32 lo = (u32)to_bf(a) | ((u32)to_bf(b) << 16);
  u32 hi = (u32)to_bf(c) | ((u32)to_bf(d) << 16);
  *(u32*)p = lo; *((u32*)p + 1) = hi;
}

DI float wredf(float v) {
  #pragma unroll
  for (int o = 32; o; o >>= 1) v += __shfl_down(v, o);
  return v;
}
DI int wredi(int v) {
  #pragma unroll
  for (int o = 32; o; o >>= 1) v += __shfl_down(v, o);
  return v;
}

typedef __attribute__((address_space(3))) void lds_void;
typedef __attribute__((address_space(1))) void glb_void;
DI void async_load16(const void* g, void* l) {
  __builtin_amdgcn_global_load_lds((glb_void*)(uintptr_t)g,
                                   (lds_void*)(u32)(uintptr_t)l, 16, 0, 0);
}

// ---------------- generic NT bf16 GEMM body (device fn) ----------------
// C[m][n] = sum_{k in [k0,k0+kLen)} A[m][k]*B[n][k]; row stride K.
template <int BM, int BN, class Epi>
DI void gemm_body(const u16* __restrict__ A, const u16* __restrict__ B,
                  int nb, int K, int k0, int kLen, Epi epi, int tile,
                  u16* As, u16* Bs)
{
  constexpr int BK = 64;
  constexpr int WM = BM / 2, WN = BN / 2;
  constexpr int FM = WM / 16, FN = WN / 16;
  constexpr int AI = (BM * 8) / 256, BI = (BN * 8) / 256;

  const int tid = threadIdx.x;
  const int w = tid >> 6, l = tid & 63;
  const int bi = tile / nb, bj = tile - bi * nb;
  const int i0 = bi * BM, j0 = bj * BN;
  const int wm = (w & 1) * WM, wn = (w >> 1) * WN;
  const int quad = l >> 4, m16 = l & 15;

  f32x4 acc[FM][FN] = {};

  for (int kb = k0; kb < k0 + kLen; kb += BK) {
    __syncthreads();
    #pragma unroll
    for (int i = 0; i < AI; ++i) {
      const int ci = (i * 4 + w) * 64 + l;
      const int r = ci >> 3;
      const int lc = (ci & 7) ^ (r & 7);
      async_load16(A + (size_t)(i0 + r) * K + kb + lc * 8, &As[(i * 4 + w) * 512]);
    }
    #pragma unroll
    for (int i = 0; i < BI; ++i) {
      const int ci = (i * 4 + w) * 64 + l;
      const int r = ci >> 3;
      const int lc = (ci & 7) ^ (r & 7);
      async_load16(B + (size_t)(j0 + r) * K + kb + lc * 8, &Bs[(i * 4 + w) * 512]);
    }
    __syncthreads();
    #pragma unroll
    for (int ks = 0; ks < 2; ++ks) {
      bf16x8 af[FM], bfv[FN];
      #pragma unroll
      for (int mi = 0; mi < FM; ++mi) {
        const int row = wm + mi * 16 + m16;
        af[mi] = *(const bf16x8*)&As[row * BK + (((ks * 4 + quad) ^ (row & 7)) * 8)];
      }
      #pragma unroll
      for (int ni = 0; ni < FN; ++ni) {
        const int row = wn + ni * 16 + m16;
        bfv[ni] = *(const bf16x8*)&Bs[row * BK + (((ks * 4 + quad) ^ (row & 7)) * 8)];
      }
      #pragma unroll
      for (int mi = 0; mi < FM; ++mi)
        #pragma unroll
        for (int ni = 0; ni < FN; ++ni)
          acc[mi][ni] = __builtin_amdgcn_mfma_f32_16x16x32_bf16(
              af[mi], bfv[ni], acc[mi][ni], 0, 0, 0);
    }
  }
  // C/D layout: col = lane&15, row = quad*4 + reg
  #pragma unroll
  for (int mi = 0; mi < FM; ++mi)
    #pragma unroll
    for (int ni = 0; ni < FN; ++ni) {
      const int rb = i0 + wm + mi * 16 + quad * 4;
      const int c  = j0 + wn + ni * 16 + m16;
      epi(rb, c, acc[mi][ni]);
    }
}

// 32x32 transpose tile (flat 256 threads); t >= 32*33 u16
DI void t32_tile(const u16* __restrict__ in, u16* __restrict__ out,
                 int R, int C, int bx, int by, u16* t) {
  int tx = threadIdx.x & 31, ty = threadIdx.x >> 5;
  int x0 = bx * 32, y0 = by * 32;
  #pragma unroll
  for (int k = 0; k < 32; k += 8)
    t[(ty + k) * 33 + tx] = in[(size_t)(y0 + ty + k) * C + x0 + tx];
  __syncthreads();
  #pragma unroll
  for (int k = 0; k < 32; k += 8)
    out[(size_t)(x0 + ty + k) * R + y0 + tx] = t[tx * 33 + ty + k];
}

// ---------------- epilogues (rb..rb+3 rows, col c) ----------------
struct EpiG0 {   // x @ [wgT|w2T|w1T]: Whg(+2 transposed) | X4att | XwT(+bias)
  u16 *whg, *whgTa, *whgTb, *x4, *xwT; const float* bias;
  DI void operator()(int r, int c, f32x4 v) const {
    if (c < 256) {
      #pragma unroll
      for (int i = 0; i < 4; ++i) whg[(r + i) * 256 + c] = to_bf(v[i]);
      store_bf4(&whgTa[(size_t)c * NN + r], v[0], v[1], v[2], v[3]);
      store_bf4(&whgTb[(size_t)c * NN + r], v[0], v[1], v[2], v[3]);
    } else if (c < 512) {
      #pragma unroll
      for (int i = 0; i < 4; ++i) x4[(r + i) * 256 + (c - 256)] = to_bf(v[i]);
    } else {
      float b = bias[c - 512];
      store_bf4(&xwT[(size_t)(c - 512) * NN + r], v[0]+b, v[1]+b, v[2]+b, v[3]+b);
    }
  }
};
struct EpiBig {  // expA @ [H|Whg] * (1/rowsum) -> G2h + G2hT + G1
  const float* rsInv; u16* g2h; u16* g2hT; float* g1;
  DI void operator()(int r, int c, f32x4 v) const {
    float w0 = v[0]*rsInv[r], w1 = v[1]*rsInv[r+1], w2 = v[2]*rsInv[r+2], w3 = v[3]*rsInv[r+3];
    if (c < 2048) {
      g2h[(size_t)r * EE + c] = to_bf(w0);
      g2h[(size_t)(r+1) * EE + c] = to_bf(w1);
      g2h[(size_t)(r+2) * EE + c] = to_bf(w2);
      g2h[(size_t)(r+3) * EE + c] = to_bf(w3);
      store_bf4(&g2hT[(size_t)c * NN + r], w0, w1, w2, w3);
    } else {
      g1[(r) * 256 + (c - 2048)] = w0;
      g1[(r+1) * 256 + (c - 2048)] = w1;
      g1[(r+2) * 256 + (c - 2048)] = w2;
      g1[(r+3) * 256 + (c - 2048)] = w3;
    }
  }
};
struct EpiEdgeT {   // [xwT|WhgTa] x att1: rows<256 -> EdgeT + Edge; else Edge2T
  u16 *edgeT, *edge2T, *edge;
  DI void operator()(int r, int c, f32x4 v) const {
    if (r < 256) {
      #pragma unroll
      for (int i = 0; i < 4; ++i) edgeT[(size_t)(r + i) * EE + c] = to_bf(v[i]);
      store_bf4(&edge[(size_t)c * 256 + r], v[0], v[1], v[2], v[3]);
    } else {
      #pragma unroll
      for (int i = 0; i < 4; ++i) edge2T[(size_t)(r - 256 + i) * EE + c] = to_bf(v[i]);
    }
  }
};
struct EpiCombine { // C1: relu(node) | elu(G1 + C2 + v) -> d_out
  const float* g1; const float* c2; float* out;
  DI void operator()(int r, int c, f32x4 v) const {
    if (c < 256) {
      #pragma unroll
      for (int i = 0; i < 4; ++i) out[(r + i) * 256 + c] = fmaxf(v[i], 0.f);
    } else {
      int d = c - 256;
      #pragma unroll
      for (int i = 0; i < 4; ++i) {
        float s = g1[(r + i) * 256 + d] + c2[(r + i) * 256 + d] + v[i];
        out[1048576 + (r + i) * 256 + d] = s > 0.f ? s : expm1f(s);
      }
    }
  }
};
struct EpiBf16 { u16* out; int ldn;
  DI void operator()(int r, int c, f32x4 v) const {
    #pragma unroll
    for (int i = 0; i < 4; ++i) out[(size_t)(r + i) * ldn + c] = to_bf(v[i]);
  } };
struct EpiBf16Scale { u16* out; int ldn; float s;
  DI void operator()(int r, int c, f32x4 v) const {
    #pragma unroll
    for (int i = 0; i < 4; ++i) out[(size_t)(r + i) * ldn + c] = to_bf(v[i] * s);
  } };
struct EpiF32 { float* out; int ldn;
  DI void operator()(int r, int c, f32x4 v) const {
    #pragma unroll
    for (int i = 0; i < 4; ++i) out[(size_t)(r + i) * ldn + c] = v[i];
  } };
struct EpiAtomF32 { float* out; int ldn;
  DI void operator()(int r, int c, f32x4 v) const {
    #pragma unroll
    for (int i = 0; i < 4; ++i) atomicAdd(&out[(size_t)(r + i) * ldn + c], v[i]);
  } };

// ---------------- GEMM wrapper: split-K or XCD swizzle ----------------
// XSW>0 (requires S==1, nb==8*XSW, grid==8*XSW*mb): xcd b&7 owns bj stripe
// [xcd*XSW, xcd*XSW+XSW) across all bi -> per-XCD B footprint fits L2.
template <int BM, int BN, int S, int LB, int XSW, class Epi>
__global__ __launch_bounds__(256, LB)
void gemm_k(const u16* __restrict__ A, const u16* __restrict__ B,
            int nb, int K, Epi epi) {
  __shared__ __align__(16) u16 smem[(BM + BN) * 64];
  int t = blockIdx.x;
  int k0 = 0, kLen = K;
  if (XSW > 0) {
    const int xcd = t & 7, idx = t >> 3;
    const int bj = xcd * XSW + idx % XSW;
    const int bi = idx / XSW;
    t = bi * nb + bj;
  } else if (S > 1) {
    const int tilesPer = gridDim.x / S;
    const int s = t / tilesPer; t -= s * tilesPer;
    kLen = K / S; k0 = s * kLen;
  }
  gemm_body<BM, BN>(A, B, nb, K, k0, kLen, epi, t, smem, smem + BM * 64);
}

// ---------------- small kernels ----------------
__global__ void k_prep(const float* wg, const float* w2, const float* w1,
                       const float* w3, const float* x, u16* wcat, u16* xb,
                       char* zbits, char* zhbt, char* zhn2) {
  int idx = blockIdx.x * 256 + threadIdx.x;
  if (blockIdx.x < 5120) {            // casts: 1310720 elements
    if (idx < 196608) {
      int blk = idx >> 16, r = idx & 65535;
      int d = r >> 8, kk = r & 255;
      const float* src = blk == 0 ? wg : blk == 1 ? w2 : w1;
      wcat[idx] = to_bf(src[kk * 256 + d]);        // transposed
    } else if (idx < 262144) {
      int r = idx - 196608;
      wcat[196608 + r] = to_bf(w3[r]);             // w3 straight
    } else {
      int r = idx - 262144;
      xb[r] = to_bf(x[r]);
    }
  } else {   // zero: 4 MB bits + 16 MB HbT + 2 MB Hn2Acc (16 B/thread)
    int z = idx - 5120 * 256;
    u32x4 zero = {0, 0, 0, 0};
    if (z < 262144)       ((u32x4*)zbits)[z] = zero;
    else if (z < 1310720) ((u32x4*)zhbt)[z - 262144] = zero;
    else                  ((u32x4*)zhn2)[z - 1310720] = zero;
  }
}

__global__ void k_scatter_diag(const int* __restrict__ hidx, u32* hbits, u32* hbitsT,
                               u16* hbT, u32* abits) {
  int k = blockIdx.x * 256 + threadIdx.x;
  if (k < NNZb) {
    int n = hidx[k], e = hidx[NNZb + k];
    atomicOr(&hbits[n * 64 + (e >> 5)], 1u << (e & 31));
    atomicOr(&hbitsT[e * 128 + (n >> 5)], 1u << (n & 31));
    hbT[(size_t)e * NN + n] = 0x3F80;            // bf16 1.0
  } else {
    int i = k - NNZb;
    if (i < NN) atomicOr(&abits[i * 128 + (i >> 5)], 1u << (i & 31));
  }
}

// blocks [0,1024): rowdots; [1024,3072): clique expansion
__global__ void k_rowclique(const u16* __restrict__ whg, const u16* __restrict__ x4,
                            const float* __restrict__ ag, const float* __restrict__ wc,
                            float* wh1, float* wh2, float* v,
                            const u32* __restrict__ hbitsT, u32* abits) {
  __shared__ int list[512];
  __shared__ int cnt;
  int tid = threadIdx.x;
  if (blockIdx.x < 1024) {
    int wv = tid >> 6, l = tid & 63;
    int row = blockIdx.x * 4 + wv;
    float s1 = 0, s2 = 0, s3 = 0;
    #pragma unroll
    for (int dd = 0; dd < 4; ++dd) {
      int d = l * 4 + dd;
      float a = from_bf(whg[row * 256 + d]);
      s1 += a * ag[d]; s2 += a * ag[256 + d];
      s3 += from_bf(x4[row * 256 + d]) * wc[d];
    }
    s1 = wredf(s1); s2 = wredf(s2); s3 = wredf(s3);
    if (l == 0) { wh1[row] = s1; wh2[row] = s2; v[row] = s3 * (1.0f / 16.0f); }
  } else {
    int e = blockIdx.x - 1024;
    if (tid == 0) cnt = 0;
    __syncthreads();
    if (tid < 128) {
      u32 w = hbitsT[e * 128 + tid];
      while (w) {
        int b = __ffs(w) - 1;
        int p = atomicAdd(&cnt, 1);
        if (p < 512) list[p] = tid * 32 + b;
        w &= w - 1;
      }
    }
    __syncthreads();
    int c = cnt < 512 ? cnt : 512;
    for (int p = tid; p < c * c; p += 256) {
      int i = list[p / c], j = list[p % c];
      atomicOr(&abits[i * 128 + (j >> 5)], 1u << (j & 31));
    }
  }
}

__global__ void k_exprows(const u32* __restrict__ abits, const float* __restrict__ wh1,
                          const float* __restrict__ wh2, u16* __restrict__ expA,
                          float* rsInv) {
  int i = blockIdx.x, tid = threadIdx.x;
  __shared__ float w2s[NN];
  __shared__ float ssum;
  for (int j = tid; j < NN; j += 256) w2s[j] = wh2[j];
  if (tid == 0) ssum = 0.f;
  __syncthreads();
  float a = wh1[i], lsum = 0.f;
  for (int j = tid; j < NN; j += 256) {
    u32 w = abits[i * 128 + (j >> 5)];
    u16 h = 0;
    if ((w >> (j & 31)) & 1) {
      float z = a + w2s[j];
      float eg = z > 0.f ? z : 0.2f * z;
      h = to_bf(__expf(eg));
      lsum += from_bf(h);
    }
    expA[(size_t)i * NN + j] = h;
  }
  lsum = wredf(lsum);
  if ((tid & 63) == 0) atomicAdd(&ssum, lsum);
  __syncthreads();
  if (tid == 0) rsInv[i] = 1.0f / ssum;
}

__global__ void k_edge_softmax(const u16* __restrict__ g2hT, const u32* __restrict__ hbitsT,
                               const float* __restrict__ v, u16* __restrict__ att1) {
  int e = blockIdx.x, tid = threadIdx.x;
  __shared__ float evals[NN];
  __shared__ u32 hw[128];
  __shared__ float s1s, s2s; __shared__ int cs;
  if (tid == 0) { s1s = 0.f; s2s = 0.f; cs = 0; }
  if (tid < 128) hw[tid] = hbitsT[e * 128 + tid];
  __syncthreads();
  float sum1 = 0.f;
  for (int j = tid; j < NN; j += 256) {
    float ev = __expf(from_bf(g2hT[(size_t)e * NN + j]));
    evals[j] = ev; sum1 += ev;
  }
  float sum2 = 0.f; int cnt = 0;
  if (tid < 128) {
    u32 w = hw[tid]; cnt = __popc(w);
    while (w) { int b = __ffs(w) - 1; sum2 += __expf(v[tid * 32 + b]); w &= w - 1; }
  }
  sum1 = wredf(sum1); sum2 = wredf(sum2); cnt = wredi(cnt);
  if ((tid & 63) == 0) { atomicAdd(&s1s, sum1); atomicAdd(&s2s, sum2); atomicAdd(&cs, cnt); }
  __syncthreads();
  float inv1 = 1.0f / s1s;
  int c = cs;
  float inv2 = c > 0 ? 1.0f / s2s : 0.0f;
  float unif = c > 0 ? 0.0f : (1.0f / (float)NN);
  for (int j = tid; j < NN; j += 256) {
    float t = evals[j] * inv1 + unif;
    if ((hw[j >> 5] >> (j & 31)) & 1) t += __expf(v[j]) * inv2;
    att1[(size_t)e * NN + j] = to_bf(t);
  }
}

// tri: edgeT-cat GEMM (256 tiles, XCD-swizzled) | Yb GEMM | Att1->Att1T
__global__ __launch_bounds__(256, 2)
void k_tri_edge(const u16* __restrict__ Fcat, const u16* __restrict__ Att1,
                EpiEdgeT e0,
                const u16* __restrict__ X4att, const u16* __restrict__ W3b,
                EpiBf16 e1,
                const u16* __restrict__ tin, u16* __restrict__ tout) {
  __shared__ __align__(16) u16 smem[192 * 64];
  int b = blockIdx.x;
  if (b < 256) {
    const int xcd = b & 7, idx = b >> 3;          // nb=32 = 8 XCD x 4 stripes
    const int t = (idx / 4) * 32 + xcd * 4 + (idx & 3);
    gemm_body<64, 64>(Fcat, Att1, 32, NN, 0, NN, e0, t, smem, smem + 64 * 64);
  }
  else if (b < 384) gemm_body<128, 64>(X4att, W3b, 4, 256, 0, 256, e1, b - 256, smem, smem + 128 * 64);
  else { int t = b - 384; t32_tile(tin, tout, EE, NN, t & 127, t >> 7, smem); }
}

// dual2: C2 GEMM (128 tiles, K=2048) | attn2 GEMM (512 tiles)
__global__ __launch_bounds__(256, 2)
void k_dual_attn2(const u16* __restrict__ Att1T, const u16* __restrict__ Edge2T,
                  EpiF32 e0,
                  const u16* __restrict__ Yb, const u16* __restrict__ Edge,
                  EpiBf16Scale e1) {
  __shared__ __align__(16) u16 smem[256 * 64];
  int b = blockIdx.x;
  if (b < 128) gemm_body<128, 64>(Att1T, Edge2T, 4, EE, 0, EE, e0, b, smem, smem + 128 * 64);
  else         gemm_body<128, 128>(Yb, Edge, 16, 256, 0, 256, e1, b - 128, smem, smem + 128 * 64);
}

__global__ void k_node_softmax(const u16* __restrict__ g2h, const u16* __restrict__ attn2,
                               const u32* __restrict__ hbits, u16* __restrict__ att2hn) {
  int n = blockIdx.x, tid = threadIdx.x;
  __shared__ float ev3[EE], ev4[EE];
  __shared__ u32 hw[64];
  __shared__ float s3s, s4s; __shared__ int cs;
  if (tid == 0) { s3s = 0.f; s4s = 0.f; cs = 0; }
  if (tid < 64) hw[tid] = hbits[n * 64 + tid];
  __syncthreads();
  float s3 = 0.f, s4 = 0.f; int cl = 0;
  for (int e = tid; e < EE; e += 256) {
    float x3 = __expf(from_bf(g2h[(size_t)n * EE + e]));
    ev3[e] = x3; s3 += x3;
    bool m = (hw[e >> 5] >> (e & 31)) & 1;
    float x4 = m ? __expf(from_bf(attn2[(size_t)n * EE + e])) : 0.f;
    ev4[e] = x4; s4 += x4; cl += m;
  }
  s3 = wredf(s3); s4 = wredf(s4); cl = wredi(cl);
  if ((tid & 63) == 0) { atomicAdd(&s3s, s3); atomicAdd(&s4s, s4); atomicAdd(&cs, cl); }
  __syncthreads();
  float inv3 = 1.0f / s3s;
  int c = cs;
  float inv4 = c > 0 ? 1.0f / s4s : 0.0f;
  float unif = c > 0 ? 0.0f : (1.0f / (float)EE);
  for (int e = tid; e < EE; e += 256)
    att2hn[(size_t)n * EE + e] = to_bf(ev3[e] * inv3 + ev4[e] * inv4 + unif);
}

__global__ void k_transpose(const u16* __restrict__ in, u16* __restrict__ out,
                            int R, int C) {
  __shared__ u16 t[32 * 33];
  t32_tile(in, out, R, C, blockIdx.x, blockIdx.y, t);
}

__global__ void k_cast_hn2(const float* __restrict__ acc, u16* __restrict__ hn2T) {
  int idx = blockIdx.x * 256 + threadIdx.x;     // 524288
  hn2T[idx] = to_bf(acc[idx]);
}

// ---------------- launch ----------------
extern "C" void kernel_launch(void* const* d_in, const int* in_sizes, int n_in,
                              void* d_out, int out_size, void* d_ws, size_t ws_size,
                              hipStream_t stream) {
  (void)in_sizes; (void)n_in; (void)out_size; (void)ws_size;
  const float* x    = (const float*)d_in[0];
  const float* w1   = (const float*)d_in[1];
  const float* w2   = (const float*)d_in[2];
  const float* w3   = (const float*)d_in[3];
  const float* wg   = (const float*)d_in[4];
  const float* ag   = (const float*)d_in[5];
  const float* wc   = (const float*)d_in[6];
  const float* bias = (const float*)d_in[7];
  const int*   hidx = (const int*)d_in[8];
  float* out = (float*)d_out;
  char* ws = (char*)d_ws;

  u32* Hbits   = (u32*)(ws + OFF_HBITS);
  u32* HbitsT  = (u32*)(ws + OFF_HBITST);
  u32* Abits   = (u32*)(ws + OFF_ABITS);
  float* Wh1   = (float*)(ws + OFF_WH1);
  float* Wh2   = (float*)(ws + OFF_WH2);
  float* V     = (float*)(ws + OFF_V);
  float* RsInv = (float*)(ws + OFF_RSINV);
  u16* Wcat    = (u16*)(ws + OFF_WCAT);
  u16* W3b     = Wcat + 196608;
  u16* Xb      = (u16*)(ws + OFF_XB);
  u16* Whg     = (u16*)(ws + OFF_WHG);
  u16* X4att   = (u16*)(ws + OFF_X4ATT);
  u16* Yb      = (u16*)(ws + OFF_YB);
  u16* XwT     = (u16*)(ws + OFF_XWT);     // Fcat = [XwT|WhgTa] contiguous
  u16* WhgTa   = (u16*)(ws + OFF_WHGTA);
  u16* HbT     = (u16*)(ws + OFF_HBT);
  u16* WhgTb   = (u16*)(ws + OFF_WHGTB);
  u16* ExpA    = (u16*)(ws + OFF_EXPA);
  u16* Att1    = (u16*)(ws + OFF_ATT1);
  u16* Att1T   = (u16*)(ws + OFF_ATT1T);
  u16* Att2hn  = (u16*)(ws + OFF_ATT2HN);
  u16* G2h     = (u16*)(ws + OFF_G2H);
  u16* G2hT    = (u16*)(ws + OFF_G2HT);
  u16* Att2hnT = (u16*)(ws + OFF_ATT2HNT);
  u16* Attn2   = (u16*)(ws + OFF_ATTN2);
  float* G1    = (float*)(ws + OFF_G1);
  float* C2    = (float*)(ws + OFF_C2);
  float* Hn2Acc = (float*)(ws + OFF_HN2ACC);
  u16* Edge    = (u16*)(ws + OFF_EDGE);
  u16* EdgeT   = (u16*)(ws + OFF_EDGET);   // [EdgeT|Hn2T] = C1 B-cat contiguous
  u16* Hn2T    = (u16*)(ws + OFF_HN2T);
  u16* Edge2T  = (u16*)(ws + OFF_EDGE2T);

  // 1. casts + zeroing (bits 4 MB, HbT 16 MB, Hn2Acc 2 MB)
  k_prep<<<10752, 256, 0, stream>>>(wg, w2, w1, w3, x, Wcat, Xb,
                                    ws + OFF_HBITS, ws + OFF_HBT, ws + OFF_HN2ACC);
  // 2. incidence bitsets + H^T + A-diagonal
  k_scatter_diag<<<272, 256, 0, stream>>>(hidx, Hbits, HbitsT, HbT, Abits);
  // 3. G0: x @ [wgT|w2T|w1T] -> Whg(+2T) | X4att | XwT(+bias)
  gemm_k<128, 64, 1, 3, 0><<<384, 256, 0, stream>>>(
      Xb, Wcat, 12, 256, EpiG0{Whg, WhgTa, WhgTb, X4att, XwT, bias});
  // 4. rowdots + clique expansion
  k_rowclique<<<3072, 256, 0, stream>>>(Whg, X4att, ag, wc, Wh1, Wh2, V,
                                        HbitsT, Abits);
  // 5. expA rows + 1/rowsum
  k_exprows<<<NN, 256, 0, stream>>>(Abits, Wh1, Wh2, ExpA, RsInv);
  // 6. big fused GEMM (XCD-swizzled: xcd owns 3-wide bj stripe, B fits L2)
  gemm_k<128, 96, 1, 3, 3><<<768, 256, 0, stream>>>(
      ExpA, HbT, 24, NN, EpiBig{RsInv, G2h, G2hT, G1});
  // 7. att1 per edge
  k_edge_softmax<<<EE, 256, 0, stream>>>(G2hT, HbitsT, V, Att1);
  // 8. tri: [EdgeT|Edge2T](+Edge) | Yb = X4att@w3^T | Att1->Att1T
  k_tri_edge<<<8576, 256, 0, stream>>>(
      XwT, Att1, EpiEdgeT{EdgeT, Edge2T, Edge},
      X4att, W3b, EpiBf16{Yb, 256},
      Att1, Att1T);
  // 9. dual2: C2 = att1^T @ edge2 | attn2 = Yb @ edge^T / temp
  k_dual_attn2<<<640, 256, 0, stream>>>(
      Att1T, Edge2T, EpiF32{C2, 256},
      Yb, Edge, EpiBf16Scale{Attn2, EE, 1.0f / 16.0f});
  // 10. att2hn per node
  k_node_softmax<<<NN, 256, 0, stream>>>(G2h, Attn2, Hbits, Att2hn);
  // 11. Att2hn -> Att2hnT
  k_transpose<<<dim3(64, 128), 256, 0, stream>>>(Att2hn, Att2hnT, NN, EE);
  // 12. hn2T = Whg^T @ att2hn: split-K4 atomics (512 blocks, 2/CU)
  gemm_k<64, 64, 4, 3, 0><<<512, 256, 0, stream>>>(
      WhgTa, Att2hnT, 32, NN, EpiAtomF32{Hn2Acc, EE});
  // 13. cast Hn2Acc -> Hn2T bf16
  k_cast_hn2<<<2048, 256, 0, stream>>>(Hn2Acc, Hn2T);
  // 14. C1 = att2hn @ [edge|hn2] with fused relu/elu combine -> d_out
  gemm_k<64, 64, 1, 2, 0><<<512, 256, 0, stream>>>(
      Att2hn, EdgeT, 8, EE, EpiCombine{G1, C2, out});
}

// Round 7
// 361.366 us; speedup vs baseline: 1.1167x; 1.0525x over previous
//
#include <hip/hip_runtime.h>
#include <cstdint>
#include <cstddef>

// ============================================================================
// ProposedConv hypergraph dual-attention (round 7):
//  - REVERT big-GEMM XCD swizzle (R6: FETCH unchanged 140 MB, dur 80->87 us;
//    blockIdx-striping does not control XCD locality here). Linear order.
//  - big GEMM in fp8 e4m3 (v_mfma_f32_16x16x32_fp8_fp8): BK=128 elements =
//    same 128 B/row byte layout as bf16 BK=64 -> same XOR-swizzle staging,
//    half staging bytes, half barrier count. expA/HbT/WhgTb produced as fp8
//    (expA 32->16 MB, HbT 16->8 MB).
//  - everything else = R6 structure (hn2T split-K4, tri/dual fusions)
// ============================================================================

#define DI __device__ __forceinline__
typedef unsigned short u16;
typedef unsigned char  u8;
typedef unsigned int   u32;
typedef __bf16 bf16x8 __attribute__((ext_vector_type(8)));
typedef float  f32x4  __attribute__((ext_vector_type(4)));
typedef u32    u32x4  __attribute__((ext_vector_type(4)));

constexpr int NN  = 4096;   // nodes
constexpr int EE  = 2048;   // hyperedges
constexpr int NNZb = 65536; // incidence nnz

// ---------------- workspace layout (bytes) ----------------
constexpr size_t MB = (size_t)1 << 20;
constexpr size_t OFF_HBITS   = 0;          // u32 [4096][64]
constexpr size_t OFF_HBITST  = 1*MB;       // u32 [2048][128]
constexpr size_t OFF_ABITS   = 2*MB;       // u32 [4096][128]; Edge reuses after exprows
constexpr size_t OFF_EDGE    = 2*MB;       //   bf16 [2048][256]
constexpr size_t OFF_WH1     = 4*MB;
constexpr size_t OFF_WH2     = 4*MB + 16384;
constexpr size_t OFF_V       = 4*MB + 32768;
constexpr size_t OFF_RSINV   = 4*MB + 49152;
constexpr size_t OFF_WCAT    = 5*MB;       // bf16 [wgT|w2T|w1T](768x256) + w3b(256x256)
constexpr size_t OFF_XB      = 6*MB;       // bf16 [4096][256]; EdgeT/Hn2T reuse after G0
constexpr size_t OFF_EDGET   = 6*MB;       //   bf16 [256][2048]
constexpr size_t OFF_HN2T    = 7*MB;       //   bf16 [256][2048] ([EdgeT|Hn2T] = C1 B-cat)
constexpr size_t OFF_WHG     = 8*MB;       // bf16 [4096][256]
constexpr size_t OFF_X4ATT   = 10*MB;      // bf16 [4096][256]
constexpr size_t OFF_YB      = 12*MB;      // bf16 [4096][256]
constexpr size_t OFF_XWT     = 14*MB;      // bf16 [256][4096] ([XwT|WhgTa] = edgeT A-cat)
constexpr size_t OFF_WHGTA   = 16*MB;      // bf16 [256][4096]
constexpr size_t OFF_HBT     = 18*MB;      // fp8 [2048][4096]; Edge2T reuses after bigGEMM
constexpr size_t OFF_EDGE2T  = 18*MB;      //   bf16 [256][2048]
constexpr size_t OFF_WHGTB   = 26*MB;      // fp8 [256][4096] ([HbT|WhgTb] = bigGEMM B-cat)
constexpr size_t OFF_EXPA    = 36*MB;      // fp8 [4096][4096] (16 MB); Att1 reuses after
constexpr size_t OFF_ATT1    = 36*MB;      //   bf16 [2048][4096]; dead after tri GEMM
constexpr size_t OFF_ATT2HN  = 36*MB;      //   bf16 [4096][2048]
constexpr size_t OFF_ATT1T   = 52*MB;      // bf16 [4096][2048]
constexpr size_t OFF_G2H     = 68*MB;      // bf16 [4096][2048]
constexpr size_t OFF_G2HT    = 84*MB;      // bf16 [2048][4096]; Att2hnT reuses
constexpr size_t OFF_ATT2HNT = 84*MB;
constexpr size_t OFF_ATTN2   = 100*MB;     // bf16 [4096][2048]
constexpr size_t OFF_G1      = 116*MB;     // f32 [4096][256] (rsInv-scaled, from EpiBig)
constexpr size_t OFF_C2      = 120*MB;     // f32 [4096][256]
constexpr size_t OFF_HN2ACC  = 124*MB;     // f32 [256][2048] (atomic; zeroed in prep)

// ---------------- helpers ----------------
DI u16 to_bf(float f) {
  union { float f; u32 u; } x; x.f = f;
  u32 r = x.u + 0x7fffu + ((x.u >> 16) & 1u);
  return (u16)(r >> 16);
}
DI float from_bf(u16 h) { union { u32 u; float f; } x; x.u = (u32)h << 16; return x.f; }
DI void store_bf4(u16* p, float a, float b, float c, float d) {  // 8B aligned store
  u32 lo = (u32)to_bf(a) | ((u32)to_bf(b) << 16);
  u32 hi = (u32)to_bf(c) | ((u32)to_bf(d) << 16);
  *(u32*)p = lo; *((u32*)p + 1) = hi;
}
DI u32 pack_fp8x4(float a, float b, float c, float d) {   // OCP e4m3fn, RNE
  int p = __builtin_amdgcn_cvt_pk_fp8_f32(a, b, 0, false);
  p = __builtin_amdgcn_cvt_pk_fp8_f32(c, d, p, true);
  return (u32)p;
}

DI float wredf(float v) {
  #pragma unroll
  for (int o = 32; o; o >>= 1) v += __shfl_down(v, o);
  return v;
}
DI int wredi(int v) {
  #pragma unroll
  for (int o = 32; o; o >>= 1) v += __shfl_down(v, o);
  return v;
}

typedef __attribute__((address_space(3))) void lds_void;
typedef __attribute__((address_space(1))) void glb_void;
DI void async_load16(const void* g, void* l) {
  __builtin_amdgcn_global_load_lds((glb_void*)(uintptr_t)g,
                                   (lds_void*)(u32)(uintptr_t)l, 16, 0, 0);
}

// ---------------- generic NT bf16 GEMM body (device fn) ----------------
// C[m][n] = sum_{k in [k0,k0+kLen)} A[m][k]*B[n][k]; row stride K.
template <int BM, int BN, class Epi>
DI void gemm_body(const u16* __restrict__ A, const u16* __restrict__ B,
                  int nb, int K, int k0, int kLen, Epi epi, int tile,
                  u16* As, u16* Bs)
{
  constexpr int BK = 64;
  constexpr int WM = BM / 2, WN = BN / 2;
  constexpr int FM = WM / 16, FN = WN / 16;
  constexpr int AI = (BM * 8) / 256, BI = (BN * 8) / 256;

  const int tid = threadIdx.x;
  const int w = tid >> 6, l = tid & 63;
  const int bi = tile / nb, bj = tile - bi * nb;
  const int i0 = bi * BM, j0 = bj * BN;
  const int wm = (w & 1) * WM, wn = (w >> 1) * WN;
  const int quad = l >> 4, m16 = l & 15;

  f32x4 acc[FM][FN] = {};

  for (int kb = k0; kb < k0 + kLen; kb += BK) {
    __syncthreads();
    #pragma unroll
    for (int i = 0; i < AI; ++i) {
      const int ci = (i * 4 + w) * 64 + l;
      const int r = ci >> 3;
      const int lc = (ci & 7) ^ (r & 7);
      async_load16(A + (size_t)(i0 + r) * K + kb + lc * 8, &As[(i * 4 + w) * 512]);
    }
    #pragma unroll
    for (int i = 0; i < BI; ++i) {
      const int ci = (i * 4 + w) * 64 + l;
      const int r = ci >> 3;
      const int lc = (ci & 7) ^ (r & 7);
      async_load16(B + (size_t)(j0 + r) * K + kb + lc * 8, &Bs[(i * 4 + w) * 512]);
    }
    __syncthreads();
    #pragma unroll
    for (int ks = 0; ks < 2; ++ks) {
      bf16x8 af[FM], bfv[FN];
      #pragma unroll
      for (int mi = 0; mi < FM; ++mi) {
        const int row = wm + mi * 16 + m16;
        af[mi] = *(const bf16x8*)&As[row * BK + (((ks * 4 + quad) ^ (row & 7)) * 8)];
      }
      #pragma unroll
      for (int ni = 0; ni < FN; ++ni) {
        const int row = wn + ni * 16 + m16;
        bfv[ni] = *(const bf16x8*)&Bs[row * BK + (((ks * 4 + quad) ^ (row & 7)) * 8)];
      }
      #pragma unroll
      for (int mi = 0; mi < FM; ++mi)
        #pragma unroll
        for (int ni = 0; ni < FN; ++ni)
          acc[mi][ni] = __builtin_amdgcn_mfma_f32_16x16x32_bf16(
              af[mi], bfv[ni], acc[mi][ni], 0, 0, 0);
    }
  }
  // C/D layout: col = lane&15, row = quad*4 + reg
  #pragma unroll
  for (int mi = 0; mi < FM; ++mi)
    #pragma unroll
    for (int ni = 0; ni < FN; ++ni) {
      const int rb = i0 + wm + mi * 16 + quad * 4;
      const int c  = j0 + wn + ni * 16 + m16;
      epi(rb, c, acc[mi][ni]);
    }
}

// 32x32 transpose tile (flat 256 threads); t >= 32*33 u16
DI void t32_tile(const u16* __restrict__ in, u16* __restrict__ out,
                 int R, int C, int bx, int by, u16* t) {
  int tx = threadIdx.x & 31, ty = threadIdx.x >> 5;
  int x0 = bx * 32, y0 = by * 32;
  #pragma unroll
  for (int k = 0; k < 32; k += 8)
    t[(ty + k) * 33 + tx] = in[(size_t)(y0 + ty + k) * C + x0 + tx];
  __syncthreads();
  #pragma unroll
  for (int k = 0; k < 32; k += 8)
    out[(size_t)(x0 + ty + k) * R + y0 + tx] = t[tx * 33 + ty + k];
}

// ---------------- epilogues (rb..rb+3 rows, col c) ----------------
struct EpiG0 {   // x @ [wgT|w2T|w1T]: Whg(+bf16 T, +fp8 T) | X4att | XwT(+bias)
  u16 *whg, *whgTa, *x4, *xwT; u8* whgTb; const float* bias;
  DI void operator()(int r, int c, f32x4 v) const {
    if (c < 256) {
      #pragma unroll
      for (int i = 0; i < 4; ++i) whg[(r + i) * 256 + c] = to_bf(v[i]);
      store_bf4(&whgTa[(size_t)c * NN + r], v[0], v[1], v[2], v[3]);
      *(u32*)&whgTb[(size_t)c * NN + r] = pack_fp8x4(v[0], v[1], v[2], v[3]);
    } else if (c < 512) {
      #pragma unroll
      for (int i = 0; i < 4; ++i) x4[(r + i) * 256 + (c - 256)] = to_bf(v[i]);
    } else {
      float b = bias[c - 512];
      store_bf4(&xwT[(size_t)(c - 512) * NN + r], v[0]+b, v[1]+b, v[2]+b, v[3]+b);
    }
  }
};
struct EpiBig {  // expA @ [H|Whg] * (1/rowsum) -> G2h + G2hT + G1
  const float* rsInv; u16* g2h; u16* g2hT; float* g1;
  DI void operator()(int r, int c, f32x4 v) const {
    float w0 = v[0]*rsInv[r], w1 = v[1]*rsInv[r+1], w2 = v[2]*rsInv[r+2], w3 = v[3]*rsInv[r+3];
    if (c < 2048) {
      g2h[(size_t)r * EE + c] = to_bf(w0);
      g2h[(size_t)(r+1) * EE + c] = to_bf(w1);
      g2h[(size_t)(r+2) * EE + c] = to_bf(w2);
      g2h[(size_t)(r+3) * EE + c] = to_bf(w3);
      store_bf4(&g2hT[(size_t)c * NN + r], w0, w1, w2, w3);
    } else {
      g1[(r) * 256 + (c - 2048)] = w0;
      g1[(r+1) * 256 + (c - 2048)] = w1;
      g1[(r+2) * 256 + (c - 2048)] = w2;
      g1[(r+3) * 256 + (c - 2048)] = w3;
    }
  }
};
struct EpiEdgeT {   // [xwT|WhgTa] x att1: rows<256 -> EdgeT + Edge; else Edge2T
  u16 *edgeT, *edge2T, *edge;
  DI void operator()(int r, int c, f32x4 v) const {
    if (r < 256) {
      #pragma unroll
      for (int i = 0; i < 4; ++i) edgeT[(size_t)(r + i) * EE + c] = to_bf(v[i]);
      store_bf4(&edge[(size_t)c * 256 + r], v[0], v[1], v[2], v[3]);
    } else {
      #pragma unroll
      for (int i = 0; i < 4; ++i) edge2T[(size_t)(r - 256 + i) * EE + c] = to_bf(v[i]);
    }
  }
};
struct EpiCombine { // C1: relu(node) | elu(G1 + C2 + v) -> d_out
  const float* g1; const float* c2; float* out;
  DI void operator()(int r, int c, f32x4 v) const {
    if (c < 256) {
      #pragma unroll
      for (int i = 0; i < 4; ++i) out[(r + i) * 256 + c] = fmaxf(v[i], 0.f);
    } else {
      int d = c - 256;
      #pragma unroll
      for (int i = 0; i < 4; ++i) {
        float s = g1[(r + i) * 256 + d] + c2[(r + i) * 256 + d] + v[i];
        out[1048576 + (r + i) * 256 + d] = s > 0.f ? s : expm1f(s);
      }
    }
  }
};
struct EpiBf16 { u16* out; int ldn;
  DI void operator()(int r, int c, f32x4 v) const {
    #pragma unroll
    for (int i = 0; i < 4; ++i) out[(size_t)(r + i) * ldn + c] = to_bf(v[i]);
  } };
struct EpiBf16Scale { u16* out; int ldn; float s;
  DI void operator()(int r, int c, f32x4 v) const {
    #pragma unroll
    for (int i = 0; i < 4; ++i) out[(size_t)(r + i) * ldn + c] = to_bf(v[i] * s);
  } };
struct EpiF32 { float* out; int ldn;
  DI void operator()(int r, int c, f32x4 v) const {
    #pragma unroll
    for (int i = 0; i < 4; ++i) out[(size_t)(r + i) * ldn + c] = v[i];
  } };
struct EpiAtomF32 { float* out; int ldn;
  DI void operator()(int r, int c, f32x4 v) const {
    #pragma unroll
    for (int i = 0; i < 4; ++i) atomicAdd(&out[(size_t)(r + i) * ldn + c], v[i]);
  } };

// ---------------- bf16 GEMM wrapper with split-K ----------------
template <int BM, int BN, int S, int LB, class Epi>
__global__ __launch_bounds__(256, LB)
void gemm_k(const u16* __restrict__ A, const u16* __restrict__ B,
            int nb, int K, Epi epi) {
  __shared__ __align__(16) u16 smem[(BM + BN) * 64];
  int t = blockIdx.x;
  int k0 = 0, kLen = K;
  if (S > 1) {
    const int tilesPer = gridDim.x / S;
    const int s = t / tilesPer; t -= s * tilesPer;
    kLen = K / S; k0 = s * kLen;
  }
  gemm_body<BM, BN>(A, B, nb, K, k0, kLen, epi, t, smem, smem + BM * 64);
}

// ---------------- fp8 big GEMM: BM=128, BN=96, BK=128 elements ----------
// A:[M,K] B:[N,K] row-major fp8 e4m3. Same 128 B/row byte layout as bf16
// BK=64 -> identical XOR chunk swizzle; fragments = b64; MFMA K=32.
template <class Epi>
__global__ __launch_bounds__(256, 3)
void gemm_f8(const u8* __restrict__ A, const u8* __restrict__ B,
             int nb, int K, Epi epi) {
  constexpr int BM = 128, BN = 96, BK = 128;
  constexpr int FM = 4, FN = 3;          // 64x48 per wave
  __shared__ __align__(16) u8 As[BM * BK];   // 16 KB
  __shared__ __align__(16) u8 Bs[BN * BK];   // 12 KB

  const int tid = threadIdx.x;
  const int w = tid >> 6, l = tid & 63;
  const int tile = blockIdx.x;
  const int bi = tile / nb, bj = tile - bi * nb;
  const int i0 = bi * BM, j0 = bj * BN;
  const int wm = (w & 1) * 64, wn = (w >> 1) * 48;
  const int quad = l >> 4, m16 = l & 15;

  f32x4 acc[FM][FN] = {};

  for (int kb = 0; kb < K; kb += BK) {
    __syncthreads();
    #pragma unroll
    for (int i = 0; i < 4; ++i) {        // A: 1024 chunks
      const int ci = (i * 4 + w) * 64 + l;
      const int r = ci >> 3;
      const int lc = (ci & 7) ^ (r & 7);
      async_load16(A + (size_t)(i0 + r) * K + kb + lc * 16, &As[(i * 4 + w) * 1024]);
    }
    #pragma unroll
    for (int i = 0; i < 3; ++i) {        // B: 768 chunks
      const int ci = (i * 4 + w) * 64 + l;
      const int r = ci >> 3;
      const int lc = (ci & 7) ^ (r & 7);
      async_load16(B + (size_t)(j0 + r) * K + kb + lc * 16, &Bs[(i * 4 + w) * 1024]);
    }
    __syncthreads();
    #pragma unroll
    for (int ks = 0; ks < 4; ++ks) {
      const int lcl = ks * 2 + (quad >> 1);          // logical 16B chunk
      const int sub = (quad & 1) * 8;
      long af[FM], bf[FN];
      #pragma unroll
      for (int mi = 0; mi < FM; ++mi) {
        const int row = wm + mi * 16 + m16;
        af[mi] = *(const long*)&As[row * BK + (lcl ^ (row & 7)) * 16 + sub];
      }
      #pragma unroll
      for (int ni = 0; ni < FN; ++ni) {
        const int row = wn + ni * 16 + m16;
        bf[ni] = *(const long*)&Bs[row * BK + (lcl ^ (row & 7)) * 16 + sub];
      }
      #pragma unroll
      for (int mi = 0; mi < FM; ++mi)
        #pragma unroll
        for (int ni = 0; ni < FN; ++ni)
          acc[mi][ni] = __builtin_amdgcn_mfma_f32_16x16x32_fp8_fp8(
              af[mi], bf[ni], acc[mi][ni], 0, 0, 0);
    }
  }
  #pragma unroll
  for (int mi = 0; mi < FM; ++mi)
    #pragma unroll
    for (int ni = 0; ni < FN; ++ni) {
      const int rb = i0 + wm + mi * 16 + quad * 4;
      const int c  = j0 + wn + ni * 16 + m16;
      epi(rb, c, acc[mi][ni]);
    }
}

// ---------------- small kernels ----------------
__global__ void k_prep(const float* wg, const float* w2, const float* w1,
                       const float* w3, const float* x, u16* wcat, u16* xb,
                       char* zbits, char* zhbt, char* zhn2) {
  int idx = blockIdx.x * 256 + threadIdx.x;
  if (blockIdx.x < 5120) {            // casts: 1310720 elements
    if (idx < 196608) {
      int blk = idx >> 16, r = idx & 65535;
      int d = r >> 8, kk = r & 255;
      const float* src = blk == 0 ? wg : blk == 1 ? w2 : w1;
      wcat[idx] = to_bf(src[kk * 256 + d]);        // transposed
    } else if (idx < 262144) {
      int r = idx - 196608;
      wcat[196608 + r] = to_bf(w3[r]);             // w3 straight
    } else {
      int r = idx - 262144;
      xb[r] = to_bf(x[r]);
    }
  } else {   // zero: 4 MB bits + 8 MB HbT(fp8) + 2 MB Hn2Acc (16 B/thread)
    int z = idx - 5120 * 256;
    u32x4 zero = {0, 0, 0, 0};
    if (z < 262144)      ((u32x4*)zbits)[z] = zero;
    else if (z < 786432) ((u32x4*)zhbt)[z - 262144] = zero;
    else                 ((u32x4*)zhn2)[z - 786432] = zero;
  }
}

__global__ void k_scatter_diag(const int* __restrict__ hidx, u32* hbits, u32* hbitsT,
                               u8* hbT, u32* abits) {
  int k = blockIdx.x * 256 + threadIdx.x;
  if (k < NNZb) {
    int n = hidx[k], e = hidx[NNZb + k];
    atomicOr(&hbits[n * 64 + (e >> 5)], 1u << (e & 31));
    atomicOr(&hbitsT[e * 128 + (n >> 5)], 1u << (n & 31));
    hbT[(size_t)e * NN + n] = 0x38;              // fp8 e4m3 1.0
  } else {
    int i = k - NNZb;
    if (i < NN) atomicOr(&abits[i * 128 + (i >> 5)], 1u << (i & 31));
  }
}

// blocks [0,1024): rowdots; [1024,3072): clique expansion
__global__ void k_rowclique(const u16* __restrict__ whg, const u16* __restrict__ x4,
                            const float* __restrict__ ag, const float* __restrict__ wc,
                            float* wh1, float* wh2, float* v,
                            const u32* __restrict__ hbitsT, u32* abits) {
  __shared__ int list[512];
  __shared__ int cnt;
  int tid = threadIdx.x;
  if (blockIdx.x < 1024) {
    int wv = tid >> 6, l = tid & 63;
    int row = blockIdx.x * 4 + wv;
    float s1 = 0, s2 = 0, s3 = 0;
    #pragma unroll
    for (int dd = 0; dd < 4; ++dd) {
      int d = l * 4 + dd;
      float a = from_bf(whg[row * 256 + d]);
      s1 += a * ag[d]; s2 += a * ag[256 + d];
      s3 += from_bf(x4[row * 256 + d]) * wc[d];
    }
    s1 = wredf(s1); s2 = wredf(s2); s3 = wredf(s3);
    if (l == 0) { wh1[row] = s1; wh2[row] = s2; v[row] = s3 * (1.0f / 16.0f); }
  } else {
    int e = blockIdx.x - 1024;
    if (tid == 0) cnt = 0;
    __syncthreads();
    if (tid < 128) {
      u32 w = hbitsT[e * 128 + tid];
      while (w) {
        int b = __ffs(w) - 1;
        int p = atomicAdd(&cnt, 1);
        if (p < 512) list[p] = tid * 32 + b;
        w &= w - 1;
      }
    }
    __syncthreads();
    int c = cnt < 512 ? cnt : 512;
    for (int p = tid; p < c * c; p += 256) {
      int i = list[p / c], j = list[p % c];
      atomicOr(&abits[i * 128 + (j >> 5)], 1u << (j & 31));
    }
  }
}

// masked exp rows -> fp8 expA + 1/rowsum (rowsum over fp8-rounded values)
__global__ void k_exprows(const u32* __restrict__ abits, const float* __restrict__ wh1,
                          const float* __restrict__ wh2, u8* __restrict__ expA,
                          float* rsInv) {
  int i = blockIdx.x, tid = threadIdx.x;
  __shared__ float w2s[NN];
  __shared__ float ssum;
  for (int j = tid; j < NN; j += 256) w2s[j] = wh2[j];
  if (tid == 0) ssum = 0.f;
  __syncthreads();
  float a = wh1[i], lsum = 0.f;
  #pragma unroll
  for (int it = 0; it < 4; ++it) {
    int j = it * 1024 + tid * 4;
    u32 w = abits[i * 128 + (j >> 5)];
    u32 m = (w >> (j & 31)) & 0xFu;
    float x0 = 0.f, x1 = 0.f, x2 = 0.f, x3 = 0.f;
    if (m & 1u) { float z = a + w2s[j];     float eg = z > 0.f ? z : 0.2f * z; x0 = __expf(eg); }
    if (m & 2u) { float z = a + w2s[j + 1]; float eg = z > 0.f ? z : 0.2f * z; x1 = __expf(eg); }
    if (m & 4u) { float z = a + w2s[j + 2]; float eg = z > 0.f ? z : 0.2f * z; x2 = __expf(eg); }
    if (m & 8u) { float z = a + w2s[j + 3]; float eg = z > 0.f ? z : 0.2f * z; x3 = __expf(eg); }
    u32 word = pack_fp8x4(x0, x1, x2, x3);
    *(u32*)&expA[(size_t)i * NN + j] = word;
    lsum += __builtin_amdgcn_cvt_f32_fp8(word, 0) + __builtin_amdgcn_cvt_f32_fp8(word, 1)
          + __builtin_amdgcn_cvt_f32_fp8(word, 2) + __builtin_amdgcn_cvt_f32_fp8(word, 3);
  }
  lsum = wredf(lsum);
  if ((tid & 63) == 0) atomicAdd(&ssum, lsum);
  __syncthreads();
  if (tid == 0) rsInv[i] = 1.0f / ssum;
}

__global__ void k_edge_softmax(const u16* __restrict__ g2hT, const u32* __restrict__ hbitsT,
                               const float* __restrict__ v, u16* __restrict__ att1) {
  int e = blockIdx.x, tid = threadIdx.x;
  __shared__ float evals[NN];
  __shared__ u32 hw[128];
  __shared__ float s1s, s2s; __shared__ int cs;
  if (tid == 0) { s1s = 0.f; s2s = 0.f; cs = 0; }
  if (tid < 128) hw[tid] = hbitsT[e * 128 + tid];
  __syncthreads();
  float sum1 = 0.f;
  for (int j = tid; j < NN; j += 256) {
    float ev = __expf(from_bf(g2hT[(size_t)e * NN + j]));
    evals[j] = ev; sum1 += ev;
  }
  float sum2 = 0.f; int cnt = 0;
  if (tid < 128) {
    u32 w = hw[tid]; cnt = __popc(w);
    while (w) { int b = __ffs(w) - 1; sum2 += __expf(v[tid * 32 + b]); w &= w - 1; }
  }
  sum1 = wredf(sum1); sum2 = wredf(sum2); cnt = wredi(cnt);
  if ((tid & 63) == 0) { atomicAdd(&s1s, sum1); atomicAdd(&s2s, sum2); atomicAdd(&cs, cnt); }
  __syncthreads();
  float inv1 = 1.0f / s1s;
  int c = cs;
  float inv2 = c > 0 ? 1.0f / s2s : 0.0f;
  float unif = c > 0 ? 0.0f : (1.0f / (float)NN);
  for (int j = tid; j < NN; j += 256) {
    float t = evals[j] * inv1 + unif;
    if ((hw[j >> 5] >> (j & 31)) & 1) t += __expf(v[j]) * inv2;
    att1[(size_t)e * NN + j] = to_bf(t);
  }
}

// tri: edgeT-cat GEMM (256 tiles, XCD-swizzled) | Yb GEMM | Att1->Att1T
__global__ __launch_bounds__(256, 2)
void k_tri_edge(const u16* __restrict__ Fcat, const u16* __restrict__ Att1,
                EpiEdgeT e0,
                const u16* __restrict__ X4att, const u16* __restrict__ W3b,
                EpiBf16 e1,
                const u16* __restrict__ tin, u16* __restrict__ tout) {
  __shared__ __align__(16) u16 smem[192 * 64];
  int b = blockIdx.x;
  if (b < 256) {
    const int xcd = b & 7, idx = b >> 3;          // nb=32 = 8 XCD x 4 stripes
    const int t = (idx / 4) * 32 + xcd * 4 + (idx & 3);
    gemm_body<64, 64>(Fcat, Att1, 32, NN, 0, NN, e0, t, smem, smem + 64 * 64);
  }
  else if (b < 384) gemm_body<128, 64>(X4att, W3b, 4, 256, 0, 256, e1, b - 256, smem, smem + 128 * 64);
  else { int t = b - 384; t32_tile(tin, tout, EE, NN, t & 127, t >> 7, smem); }
}

// dual2: C2 GEMM (128 tiles, K=2048) | attn2 GEMM (512 tiles)
__global__ __launch_bounds__(256, 2)
void k_dual_attn2(const u16* __restrict__ Att1T, const u16* __restrict__ Edge2T,
                  EpiF32 e0,
                  const u16* __restrict__ Yb, const u16* __restrict__ Edge,
                  EpiBf16Scale e1) {
  __shared__ __align__(16) u16 smem[256 * 64];
  int b = blockIdx.x;
  if (b < 128) gemm_body<128, 64>(Att1T, Edge2T, 4, EE, 0, EE, e0, b, smem, smem + 128 * 64);
  else         gemm_body<128, 128>(Yb, Edge, 16, 256, 0, 256, e1, b - 128, smem, smem + 128 * 64);
}

__global__ void k_node_softmax(const u16* __restrict__ g2h, const u16* __restrict__ attn2,
                               const u32* __restrict__ hbits, u16* __restrict__ att2hn) {
  int n = blockIdx.x, tid = threadIdx.x;
  __shared__ float ev3[EE], ev4[EE];
  __shared__ u32 hw[64];
  __shared__ float s3s, s4s; __shared__ int cs;
  if (tid == 0) { s3s = 0.f; s4s = 0.f; cs = 0; }
  if (tid < 64) hw[tid] = hbits[n * 64 + tid];
  __syncthreads();
  float s3 = 0.f, s4 = 0.f; int cl = 0;
  for (int e = tid; e < EE; e += 256) {
    float x3 = __expf(from_bf(g2h[(size_t)n * EE + e]));
    ev3[e] = x3; s3 += x3;
    bool m = (hw[e >> 5] >> (e & 31)) & 1;
    float x4 = m ? __expf(from_bf(attn2[(size_t)n * EE + e])) : 0.f;
    ev4[e] = x4; s4 += x4; cl += m;
  }
  s3 = wredf(s3); s4 = wredf(s4); cl = wredi(cl);
  if ((tid & 63) == 0) { atomicAdd(&s3s, s3); atomicAdd(&s4s, s4); atomicAdd(&cs, cl); }
  __syncthreads();
  float inv3 = 1.0f / s3s;
  int c = cs;
  float inv4 = c > 0 ? 1.0f / s4s : 0.0f;
  float unif = c > 0 ? 0.0f : (1.0f / (float)EE);
  for (int e = tid; e < EE; e += 256)
    att2hn[(size_t)n * EE + e] = to_bf(ev3[e] * inv3 + ev4[e] * inv4 + unif);
}

__global__ void k_transpose(const u16* __restrict__ in, u16* __restrict__ out,
                            int R, int C) {
  __shared__ u16 t[32 * 33];
  t32_tile(in, out, R, C, blockIdx.x, blockIdx.y, t);
}

__global__ void k_cast_hn2(const float* __restrict__ acc, u16* __restrict__ hn2T) {
  int idx = blockIdx.x * 256 + threadIdx.x;     // 524288
  hn2T[idx] = to_bf(acc[idx]);
}

// ---------------- launch ----------------
extern "C" void kernel_launch(void* const* d_in, const int* in_sizes, int n_in,
                              void* d_out, int out_size, void* d_ws, size_t ws_size,
                              hipStream_t stream) {
  (void)in_sizes; (void)n_in; (void)out_size; (void)ws_size;
  const float* x    = (const float*)d_in[0];
  const float* w1   = (const float*)d_in[1];
  const float* w2   = (const float*)d_in[2];
  const float* w3   = (const float*)d_in[3];
  const float* wg   = (const float*)d_in[4];
  const float* ag   = (const float*)d_in[5];
  const float* wc   = (const float*)d_in[6];
  const float* bias = (const float*)d_in[7];
  const int*   hidx = (const int*)d_in[8];
  float* out = (float*)d_out;
  char* ws = (char*)d_ws;

  u32* Hbits   = (u32*)(ws + OFF_HBITS);
  u32* HbitsT  = (u32*)(ws + OFF_HBITST);
  u32* Abits   = (u32*)(ws + OFF_ABITS);
  float* Wh1   = (float*)(ws + OFF_WH1);
  float* Wh2   = (float*)(ws + OFF_WH2);
  float* V     = (float*)(ws + OFF_V);
  float* RsInv = (float*)(ws + OFF_RSINV);
  u16* Wcat    = (u16*)(ws + OFF_WCAT);
  u16* W3b     = Wcat + 196608;
  u16* Xb      = (u16*)(ws + OFF_XB);
  u16* Whg     = (u16*)(ws + OFF_WHG);
  u16* X4att   = (u16*)(ws + OFF_X4ATT);
  u16* Yb      = (u16*)(ws + OFF_YB);
  u16* XwT     = (u16*)(ws + OFF_XWT);     // Fcat = [XwT|WhgTa] contiguous
  u16* WhgTa   = (u16*)(ws + OFF_WHGTA);
  u8*  HbT8    = (u8*)(ws + OFF_HBT);      // [HbT|WhgTb] fp8 = bigGEMM B-cat
  u8*  WhgTb8  = (u8*)(ws + OFF_WHGTB);
  u8*  ExpA8   = (u8*)(ws + OFF_EXPA);
  u16* Att1    = (u16*)(ws + OFF_ATT1);
  u16* Att1T   = (u16*)(ws + OFF_ATT1T);
  u16* Att2hn  = (u16*)(ws + OFF_ATT2HN);
  u16* G2h     = (u16*)(ws + OFF_G2H);
  u16* G2hT    = (u16*)(ws + OFF_G2HT);
  u16* Att2hnT = (u16*)(ws + OFF_ATT2HNT);
  u16* Attn2   = (u16*)(ws + OFF_ATTN2);
  float* G1    = (float*)(ws + OFF_G1);
  float* C2    = (float*)(ws + OFF_C2);
  float* Hn2Acc = (float*)(ws + OFF_HN2ACC);
  u16* Edge    = (u16*)(ws + OFF_EDGE);
  u16* EdgeT   = (u16*)(ws + OFF_EDGET);   // [EdgeT|Hn2T] = C1 B-cat contiguous
  u16* Hn2T    = (u16*)(ws + OFF_HN2T);
  u16* Edge2T  = (u16*)(ws + OFF_EDGE2T);

  // 1. casts + zeroing (bits 4 MB, HbT 8 MB fp8, Hn2Acc 2 MB)
  k_prep<<<8704, 256, 0, stream>>>(wg, w2, w1, w3, x, Wcat, Xb,
                                   ws + OFF_HBITS, ws + OFF_HBT, ws + OFF_HN2ACC);
  // 2. incidence bitsets + H^T(fp8) + A-diagonal
  k_scatter_diag<<<272, 256, 0, stream>>>(hidx, Hbits, HbitsT, HbT8, Abits);
  // 3. G0: x @ [wgT|w2T|w1T] -> Whg(+bf16 T, +fp8 T) | X4att | XwT(+bias)
  gemm_k<128, 64, 1, 3><<<384, 256, 0, stream>>>(
      Xb, Wcat, 12, 256, EpiG0{Whg, WhgTa, X4att, XwT, WhgTb8, bias});
  // 4. rowdots + clique expansion
  k_rowclique<<<3072, 256, 0, stream>>>(Whg, X4att, ag, wc, Wh1, Wh2, V,
                                        HbitsT, Abits);
  // 5. expA rows (fp8) + 1/rowsum
  k_exprows<<<NN, 256, 0, stream>>>(Abits, Wh1, Wh2, ExpA8, RsInv);
  // 6. big fused GEMM in fp8 (linear tile order — R6 swizzle reverted)
  gemm_f8<<<768, 256, 0, stream>>>(
      ExpA8, HbT8, 24, NN, EpiBig{RsInv, G2h, G2hT, G1});
  // 7. att1 per edge
  k_edge_softmax<<<EE, 256, 0, stream>>>(G2hT, HbitsT, V, Att1);
  // 8. tri: [EdgeT|Edge2T](+Edge) | Yb = X4att@w3^T | Att1->Att1T
  k_tri_edge<<<8576, 256, 0, stream>>>(
      XwT, Att1, EpiEdgeT{EdgeT, Edge2T, Edge},
      X4att, W3b, EpiBf16{Yb, 256},
      Att1, Att1T);
  // 9. dual2: C2 = att1^T @ edge2 | attn2 = Yb @ edge^T / temp
  k_dual_attn2<<<640, 256, 0, stream>>>(
      Att1T, Edge2T, EpiF32{C2, 256},
      Yb, Edge, EpiBf16Scale{Attn2, EE, 1.0f / 16.0f});
  // 10. att2hn per node
  k_node_softmax<<<NN, 256, 0, stream>>>(G2h, Attn2, Hbits, Att2hn);
  // 11. Att2hn -> Att2hnT
  k_transpose<<<dim3(64, 128), 256, 0, stream>>>(Att2hn, Att2hnT, NN, EE);
  // 12. hn2T = Whg^T @ att2hn: split-K4 atomics (512 blocks)
  gemm_k<64, 64, 4, 3><<<512, 256, 0, stream>>>(
      WhgTa, Att2hnT, 32, NN, EpiAtomF32{Hn2Acc, EE});
  // 13. cast Hn2Acc -> Hn2T bf16
  k_cast_hn2<<<2048, 256, 0, stream>>>(Hn2Acc, Hn2T);
  // 14. C1 = att2hn @ [edge|hn2] with fused relu/elu combine -> d_out
  gemm_k<64, 64, 1, 2><<<512, 256, 0, stream>>>(
      Att2hn, EdgeT, 8, EE, EpiCombine{G1, C2, out});
}

// Round 8
// 345.267 us; speedup vs baseline: 1.1688x; 1.0466x over previous
//
#include <hip/hip_runtime.h>
#include <cstdint>
#include <cstddef>

// ============================================================================
// ProposedConv hypergraph dual-attention (round 8):
//  - big GEMM: fp8 -> MX-scaled fp8 K=128 (v_mfma_scale_f32_16x16x128_f8f6f4,
//    unit E8M0 scales). 2x MFMA rate (m148: 995->1628 TF) AND kills the
//    structural ds_read_b64 4-way bank conflict of R7 (fragments are now two
//    contiguous ds_read_b128 at 16B-chunk granularity -> conflict-free).
//  - everything else identical to R7
// ============================================================================

#define DI __device__ __forceinline__
typedef unsigned short u16;
typedef unsigned char  u8;
typedef unsigned int   u32;
typedef __bf16 bf16x8 __attribute__((ext_vector_type(8)));
typedef float  f32x4  __attribute__((ext_vector_type(4)));
typedef u32    u32x4  __attribute__((ext_vector_type(4)));
typedef int    i32x4  __attribute__((ext_vector_type(4)));
typedef int    i32x8  __attribute__((ext_vector_type(8)));

constexpr int NN  = 4096;   // nodes
constexpr int EE  = 2048;   // hyperedges
constexpr int NNZb = 65536; // incidence nnz

// ---------------- workspace layout (bytes) ----------------
constexpr size_t MB = (size_t)1 << 20;
constexpr size_t OFF_HBITS   = 0;          // u32 [4096][64]
constexpr size_t OFF_HBITST  = 1*MB;       // u32 [2048][128]
constexpr size_t OFF_ABITS   = 2*MB;       // u32 [4096][128]; Edge reuses after exprows
constexpr size_t OFF_EDGE    = 2*MB;       //   bf16 [2048][256]
constexpr size_t OFF_WH1     = 4*MB;
constexpr size_t OFF_WH2     = 4*MB + 16384;
constexpr size_t OFF_V       = 4*MB + 32768;
constexpr size_t OFF_RSINV   = 4*MB + 49152;
constexpr size_t OFF_WCAT    = 5*MB;       // bf16 [wgT|w2T|w1T](768x256) + w3b(256x256)
constexpr size_t OFF_XB      = 6*MB;       // bf16 [4096][256]; EdgeT/Hn2T reuse after G0
constexpr size_t OFF_EDGET   = 6*MB;       //   bf16 [256][2048]
constexpr size_t OFF_HN2T    = 7*MB;       //   bf16 [256][2048] ([EdgeT|Hn2T] = C1 B-cat)
constexpr size_t OFF_WHG     = 8*MB;       // bf16 [4096][256]
constexpr size_t OFF_X4ATT   = 10*MB;      // bf16 [4096][256]
constexpr size_t OFF_YB      = 12*MB;      // bf16 [4096][256]
constexpr size_t OFF_XWT     = 14*MB;      // bf16 [256][4096] ([XwT|WhgTa] = edgeT A-cat)
constexpr size_t OFF_WHGTA   = 16*MB;      // bf16 [256][4096]
constexpr size_t OFF_HBT     = 18*MB;      // fp8 [2048][4096]; Edge2T reuses after bigGEMM
constexpr size_t OFF_EDGE2T  = 18*MB;      //   bf16 [256][2048]
constexpr size_t OFF_WHGTB   = 26*MB;      // fp8 [256][4096] ([HbT|WhgTb] = bigGEMM B-cat)
constexpr size_t OFF_EXPA    = 36*MB;      // fp8 [4096][4096] (16 MB); Att1 reuses after
constexpr size_t OFF_ATT1    = 36*MB;      //   bf16 [2048][4096]; dead after tri GEMM
constexpr size_t OFF_ATT2HN  = 36*MB;      //   bf16 [4096][2048]
constexpr size_t OFF_ATT1T   = 52*MB;      // bf16 [4096][2048]
constexpr size_t OFF_G2H     = 68*MB;      // bf16 [4096][2048]
constexpr size_t OFF_G2HT    = 84*MB;      // bf16 [2048][4096]; Att2hnT reuses
constexpr size_t OFF_ATT2HNT = 84*MB;
constexpr size_t OFF_ATTN2   = 100*MB;     // bf16 [4096][2048]
constexpr size_t OFF_G1      = 116*MB;     // f32 [4096][256] (rsInv-scaled, from EpiBig)
constexpr size_t OFF_C2      = 120*MB;     // f32 [4096][256]
constexpr size_t OFF_HN2ACC  = 124*MB;     // f32 [256][2048] (atomic; zeroed in prep)

// ---------------- helpers ----------------
DI u16 to_bf(float f) {
  union { float f; u32 u; } x; x.f = f;
  u32 r = x.u + 0x7fffu + ((x.u >> 16) & 1u);
  return (u16)(r >> 16);
}
DI float from_bf(u16 h) { union { u32 u; float f; } x; x.u = (u32)h << 16; return x.f; }
DI void store_bf4(u16* p, float a, float b, float c, float d) {  // 8B aligned store
  u32 lo = (u32)to_bf(a) | ((u32)to_bf(b) << 16);
  u32 hi = (u32)to_bf(c) | ((u32)to_bf(d) << 16);
  *(u32*)p = lo; *((u32*)p + 1) = hi;
}
DI u32 pack_fp8x4(float a, float b, float c, float d) {   // OCP e4m3fn, RNE
  int p = __builtin_amdgcn_cvt_pk_fp8_f32(a, b, 0, false);
  p = __builtin_amdgcn_cvt_pk_fp8_f32(c, d, p, true);
  return (u32)p;
}

DI float wredf(float v) {
  #pragma unroll
  for (int o = 32; o; o >>= 1) v += __shfl_down(v, o);
  return v;
}
DI int wredi(int v) {
  #pragma unroll
  for (int o = 32; o; o >>= 1) v += __shfl_down(v, o);
  return v;
}

typedef __attribute__((address_space(3))) void lds_void;
typedef __attribute__((address_space(1))) void glb_void;
DI void async_load16(const void* g, void* l) {
  __builtin_amdgcn_global_load_lds((glb_void*)(uintptr_t)g,
                                   (lds_void*)(u32)(uintptr_t)l, 16, 0, 0);
}

// ---------------- generic NT bf16 GEMM body (device fn) ----------------
// C[m][n] = sum_{k in [k0,k0+kLen)} A[m][k]*B[n][k]; row stride K.
template <int BM, int BN, class Epi>
DI void gemm_body(const u16* __restrict__ A, const u16* __restrict__ B,
                  int nb, int K, int k0, int kLen, Epi epi, int tile,
                  u16* As, u16* Bs)
{
  constexpr int BK = 64;
  constexpr int WM = BM / 2, WN = BN / 2;
  constexpr int FM = WM / 16, FN = WN / 16;
  constexpr int AI = (BM * 8) / 256, BI = (BN * 8) / 256;

  const int tid = threadIdx.x;
  const int w = tid >> 6, l = tid & 63;
  const int bi = tile / nb, bj = tile - bi * nb;
  const int i0 = bi * BM, j0 = bj * BN;
  const int wm = (w & 1) * WM, wn = (w >> 1) * WN;
  const int quad = l >> 4, m16 = l & 15;

  f32x4 acc[FM][FN] = {};

  for (int kb = k0; kb < k0 + kLen; kb += BK) {
    __syncthreads();
    #pragma unroll
    for (int i = 0; i < AI; ++i) {
      const int ci = (i * 4 + w) * 64 + l;
      const int r = ci >> 3;
      const int lc = (ci & 7) ^ (r & 7);
      async_load16(A + (size_t)(i0 + r) * K + kb + lc * 8, &As[(i * 4 + w) * 512]);
    }
    #pragma unroll
    for (int i = 0; i < BI; ++i) {
      const int ci = (i * 4 + w) * 64 + l;
      const int r = ci >> 3;
      const int lc = (ci & 7) ^ (r & 7);
      async_load16(B + (size_t)(j0 + r) * K + kb + lc * 8, &Bs[(i * 4 + w) * 512]);
    }
    __syncthreads();
    #pragma unroll
    for (int ks = 0; ks < 2; ++ks) {
      bf16x8 af[FM], bfv[FN];
      #pragma unroll
      for (int mi = 0; mi < FM; ++mi) {
        const int row = wm + mi * 16 + m16;
        af[mi] = *(const bf16x8*)&As[row * BK + (((ks * 4 + quad) ^ (row & 7)) * 8)];
      }
      #pragma unroll
      for (int ni = 0; ni < FN; ++ni) {
        const int row = wn + ni * 16 + m16;
        bfv[ni] = *(const bf16x8*)&Bs[row * BK + (((ks * 4 + quad) ^ (row & 7)) * 8)];
      }
      #pragma unroll
      for (int mi = 0; mi < FM; ++mi)
        #pragma unroll
        for (int ni = 0; ni < FN; ++ni)
          acc[mi][ni] = __builtin_amdgcn_mfma_f32_16x16x32_bf16(
              af[mi], bfv[ni], acc[mi][ni], 0, 0, 0);
    }
  }
  // C/D layout: col = lane&15, row = quad*4 + reg
  #pragma unroll
  for (int mi = 0; mi < FM; ++mi)
    #pragma unroll
    for (int ni = 0; ni < FN; ++ni) {
      const int rb = i0 + wm + mi * 16 + quad * 4;
      const int c  = j0 + wn + ni * 16 + m16;
      epi(rb, c, acc[mi][ni]);
    }
}

// 32x32 transpose tile (flat 256 threads); t >= 32*33 u16
DI void t32_tile(const u16* __restrict__ in, u16* __restrict__ out,
                 int R, int C, int bx, int by, u16* t) {
  int tx = threadIdx.x & 31, ty = threadIdx.x >> 5;
  int x0 = bx * 32, y0 = by * 32;
  #pragma unroll
  for (int k = 0; k < 32; k += 8)
    t[(ty + k) * 33 + tx] = in[(size_t)(y0 + ty + k) * C + x0 + tx];
  __syncthreads();
  #pragma unroll
  for (int k = 0; k < 32; k += 8)
    out[(size_t)(x0 + ty + k) * R + y0 + tx] = t[tx * 33 + ty + k];
}

// ---------------- epilogues (rb..rb+3 rows, col c) ----------------
struct EpiG0 {   // x @ [wgT|w2T|w1T]: Whg(+bf16 T, +fp8 T) | X4att | XwT(+bias)
  u16 *whg, *whgTa, *x4, *xwT; u8* whgTb; const float* bias;
  DI void operator()(int r, int c, f32x4 v) const {
    if (c < 256) {
      #pragma unroll
      for (int i = 0; i < 4; ++i) whg[(r + i) * 256 + c] = to_bf(v[i]);
      store_bf4(&whgTa[(size_t)c * NN + r], v[0], v[1], v[2], v[3]);
      *(u32*)&whgTb[(size_t)c * NN + r] = pack_fp8x4(v[0], v[1], v[2], v[3]);
    } else if (c < 512) {
      #pragma unroll
      for (int i = 0; i < 4; ++i) x4[(r + i) * 256 + (c - 256)] = to_bf(v[i]);
    } else {
      float b = bias[c - 512];
      store_bf4(&xwT[(size_t)(c - 512) * NN + r], v[0]+b, v[1]+b, v[2]+b, v[3]+b);
    }
  }
};
struct EpiBig {  // expA @ [H|Whg] * (1/rowsum) -> G2h + G2hT + G1
  const float* rsInv; u16* g2h; u16* g2hT; float* g1;
  DI void operator()(int r, int c, f32x4 v) const {
    float w0 = v[0]*rsInv[r], w1 = v[1]*rsInv[r+1], w2 = v[2]*rsInv[r+2], w3 = v[3]*rsInv[r+3];
    if (c < 2048) {
      g2h[(size_t)r * EE + c] = to_bf(w0);
      g2h[(size_t)(r+1) * EE + c] = to_bf(w1);
      g2h[(size_t)(r+2) * EE + c] = to_bf(w2);
      g2h[(size_t)(r+3) * EE + c] = to_bf(w3);
      store_bf4(&g2hT[(size_t)c * NN + r], w0, w1, w2, w3);
    } else {
      g1[(r) * 256 + (c - 2048)] = w0;
      g1[(r+1) * 256 + (c - 2048)] = w1;
      g1[(r+2) * 256 + (c - 2048)] = w2;
      g1[(r+3) * 256 + (c - 2048)] = w3;
    }
  }
};
struct EpiEdgeT {   // [xwT|WhgTa] x att1: rows<256 -> EdgeT + Edge; else Edge2T
  u16 *edgeT, *edge2T, *edge;
  DI void operator()(int r, int c, f32x4 v) const {
    if (r < 256) {
      #pragma unroll
      for (int i = 0; i < 4; ++i) edgeT[(size_t)(r + i) * EE + c] = to_bf(v[i]);
      store_bf4(&edge[(size_t)c * 256 + r], v[0], v[1], v[2], v[3]);
    } else {
      #pragma unroll
      for (int i = 0; i < 4; ++i) edge2T[(size_t)(r - 256 + i) * EE + c] = to_bf(v[i]);
    }
  }
};
struct EpiCombine { // C1: relu(node) | elu(G1 + C2 + v) -> d_out
  const float* g1; const float* c2; float* out;
  DI void operator()(int r, int c, f32x4 v) const {
    if (c < 256) {
      #pragma unroll
      for (int i = 0; i < 4; ++i) out[(r + i) * 256 + c] = fmaxf(v[i], 0.f);
    } else {
      int d = c - 256;
      #pragma unroll
      for (int i = 0; i < 4; ++i) {
        float s = g1[(r + i) * 256 + d] + c2[(r + i) * 256 + d] + v[i];
        out[1048576 + (r + i) * 256 + d] = s > 0.f ? s : expm1f(s);
      }
    }
  }
};
struct EpiBf16 { u16* out; int ldn;
  DI void operator()(int r, int c, f32x4 v) const {
    #pragma unroll
    for (int i = 0; i < 4; ++i) out[(size_t)(r + i) * ldn + c] = to_bf(v[i]);
  } };
struct EpiBf16Scale { u16* out; int ldn; float s;
  DI void operator()(int r, int c, f32x4 v) const {
    #pragma unroll
    for (int i = 0; i < 4; ++i) out[(size_t)(r + i) * ldn + c] = to_bf(v[i] * s);
  } };
struct EpiF32 { float* out; int ldn;
  DI void operator()(int r, int c, f32x4 v) const {
    #pragma unroll
    for (int i = 0; i < 4; ++i) out[(size_t)(r + i) * ldn + c] = v[i];
  } };
struct EpiAtomF32 { float* out; int ldn;
  DI void operator()(int r, int c, f32x4 v) const {
    #pragma unroll
    for (int i = 0; i < 4; ++i) atomicAdd(&out[(size_t)(r + i) * ldn + c], v[i]);
  } };

// ---------------- bf16 GEMM wrapper with split-K ----------------
template <int BM, int BN, int S, int LB, class Epi>
__global__ __launch_bounds__(256, LB)
void gemm_k(const u16* __restrict__ A, const u16* __restrict__ B,
            int nb, int K, Epi epi) {
  __shared__ __align__(16) u16 smem[(BM + BN) * 64];
  int t = blockIdx.x;
  int k0 = 0, kLen = K;
  if (S > 1) {
    const int tilesPer = gridDim.x / S;
    const int s = t / tilesPer; t -= s * tilesPer;
    kLen = K / S; k0 = s * kLen;
  }
  gemm_body<BM, BN>(A, B, nb, K, k0, kLen, epi, t, smem, smem + BM * 64);
}

// ---------------- MX-fp8 big GEMM: BM=128, BN=96, BK=128 ----------------
// A:[M,K] B:[N,K] row-major fp8 e4m3, unit E8M0 scales (0x7F = 2^0).
// v_mfma_scale_f32_16x16x128_f8f6f4: 32 B/lane fragments = two contiguous
// ds_read_b128 at 16B-chunk granularity (conflict-free, unlike R7's b64).
template <class Epi>
__global__ __launch_bounds__(256, 3)
void gemm_mx(const u8* __restrict__ A, const u8* __restrict__ B,
             int nb, int K, Epi epi) {
  constexpr int BM = 128, BN = 96, BK = 128;
  constexpr int FM = 4, FN = 3;          // 64x48 per wave
  __shared__ __align__(16) u8 As[BM * BK];   // 16 KB
  __shared__ __align__(16) u8 Bs[BN * BK];   // 12 KB

  const int tid = threadIdx.x;
  const int w = tid >> 6, l = tid & 63;
  const int tile = blockIdx.x;
  const int bi = tile / nb, bj = tile - bi * nb;
  const int i0 = bi * BM, j0 = bj * BN;
  const int wm = (w & 1) * 64, wn = (w >> 1) * 48;
  const int quad = l >> 4, m16 = l & 15;

  f32x4 acc[FM][FN] = {};

  for (int kb = 0; kb < K; kb += BK) {
    __syncthreads();
    #pragma unroll
    for (int i = 0; i < 4; ++i) {        // A: 1024 chunks
      const int ci = (i * 4 + w) * 64 + l;
      const int r = ci >> 3;
      const int lc = (ci & 7) ^ (r & 7);
      async_load16(A + (size_t)(i0 + r) * K + kb + lc * 16, &As[(i * 4 + w) * 1024]);
    }
    #pragma unroll
    for (int i = 0; i < 3; ++i) {        // B: 768 chunks
      const int ci = (i * 4 + w) * 64 + l;
      const int r = ci >> 3;
      const int lc = (ci & 7) ^ (r & 7);
      async_load16(B + (size_t)(j0 + r) * K + kb + lc * 16, &Bs[(i * 4 + w) * 1024]);
    }
    __syncthreads();
    // one K=128 MFMA step: lane (m16,quad) needs k in [quad*32, quad*32+32)
    // = logical 16B chunks 2*quad, 2*quad+1
    i32x8 af[FM], bf[FN];
    #pragma unroll
    for (int mi = 0; mi < FM; ++mi) {
      const int row = wm + mi * 16 + m16;
      const i32x4 lo = *(const i32x4*)&As[row * BK + ((quad * 2) ^ (row & 7)) * 16];
      const i32x4 hi = *(const i32x4*)&As[row * BK + ((quad * 2 + 1) ^ (row & 7)) * 16];
      af[mi][0] = lo[0]; af[mi][1] = lo[1]; af[mi][2] = lo[2]; af[mi][3] = lo[3];
      af[mi][4] = hi[0]; af[mi][5] = hi[1]; af[mi][6] = hi[2]; af[mi][7] = hi[3];
    }
    #pragma unroll
    for (int ni = 0; ni < FN; ++ni) {
      const int row = wn + ni * 16 + m16;
      const i32x4 lo = *(const i32x4*)&Bs[row * BK + ((quad * 2) ^ (row & 7)) * 16];
      const i32x4 hi = *(const i32x4*)&Bs[row * BK + ((quad * 2 + 1) ^ (row & 7)) * 16];
      bf[ni][0] = lo[0]; bf[ni][1] = lo[1]; bf[ni][2] = lo[2]; bf[ni][3] = lo[3];
      bf[ni][4] = hi[0]; bf[ni][5] = hi[1]; bf[ni][6] = hi[2]; bf[ni][7] = hi[3];
    }
    #pragma unroll
    for (int mi = 0; mi < FM; ++mi)
      #pragma unroll
      for (int ni = 0; ni < FN; ++ni)
        acc[mi][ni] = __builtin_amdgcn_mfma_scale_f32_16x16x128_f8f6f4(
            af[mi], bf[ni], acc[mi][ni], 0, 0,      // fmt A=fp8, B=fp8
            0, 0x7F7F7F7F, 0, 0x7F7F7F7F);          // unit scales
  }
  // C/D layout: col = lane&15, row = quad*4 + reg (shape-determined)
  #pragma unroll
  for (int mi = 0; mi < FM; ++mi)
    #pragma unroll
    for (int ni = 0; ni < FN; ++ni) {
      const int rb = i0 + wm + mi * 16 + quad * 4;
      const int c  = j0 + wn + ni * 16 + m16;
      epi(rb, c, acc[mi][ni]);
    }
}

// ---------------- small kernels ----------------
__global__ void k_prep(const float* wg, const float* w2, const float* w1,
                       const float* w3, const float* x, u16* wcat, u16* xb,
                       char* zbits, char* zhbt, char* zhn2) {
  int idx = blockIdx.x * 256 + threadIdx.x;
  if (blockIdx.x < 5120) {            // casts: 1310720 elements
    if (idx < 196608) {
      int blk = idx >> 16, r = idx & 65535;
      int d = r >> 8, kk = r & 255;
      const float* src = blk == 0 ? wg : blk == 1 ? w2 : w1;
      wcat[idx] = to_bf(src[kk * 256 + d]);        // transposed
    } else if (idx < 262144) {
      int r = idx - 196608;
      wcat[196608 + r] = to_bf(w3[r]);             // w3 straight
    } else {
      int r = idx - 262144;
      xb[r] = to_bf(x[r]);
    }
  } else {   // zero: 4 MB bits + 8 MB HbT(fp8) + 2 MB Hn2Acc (16 B/thread)
    int z = idx - 5120 * 256;
    u32x4 zero = {0, 0, 0, 0};
    if (z < 262144)      ((u32x4*)zbits)[z] = zero;
    else if (z < 786432) ((u32x4*)zhbt)[z - 262144] = zero;
    else                 ((u32x4*)zhn2)[z - 786432] = zero;
  }
}

__global__ void k_scatter_diag(const int* __restrict__ hidx, u32* hbits, u32* hbitsT,
                               u8* hbT, u32* abits) {
  int k = blockIdx.x * 256 + threadIdx.x;
  if (k < NNZb) {
    int n = hidx[k], e = hidx[NNZb + k];
    atomicOr(&hbits[n * 64 + (e >> 5)], 1u << (e & 31));
    atomicOr(&hbitsT[e * 128 + (n >> 5)], 1u << (n & 31));
    hbT[(size_t)e * NN + n] = 0x38;              // fp8 e4m3 1.0
  } else {
    int i = k - NNZb;
    if (i < NN) atomicOr(&abits[i * 128 + (i >> 5)], 1u << (i & 31));
  }
}

// blocks [0,1024): rowdots; [1024,3072): clique expansion
__global__ void k_rowclique(const u16* __restrict__ whg, const u16* __restrict__ x4,
                            const float* __restrict__ ag, const float* __restrict__ wc,
                            float* wh1, float* wh2, float* v,
                            const u32* __restrict__ hbitsT, u32* abits) {
  __shared__ int list[512];
  __shared__ int cnt;
  int tid = threadIdx.x;
  if (blockIdx.x < 1024) {
    int wv = tid >> 6, l = tid & 63;
    int row = blockIdx.x * 4 + wv;
    float s1 = 0, s2 = 0, s3 = 0;
    #pragma unroll
    for (int dd = 0; dd < 4; ++dd) {
      int d = l * 4 + dd;
      float a = from_bf(whg[row * 256 + d]);
      s1 += a * ag[d]; s2 += a * ag[256 + d];
      s3 += from_bf(x4[row * 256 + d]) * wc[d];
    }
    s1 = wredf(s1); s2 = wredf(s2); s3 = wredf(s3);
    if (l == 0) { wh1[row] = s1; wh2[row] = s2; v[row] = s3 * (1.0f / 16.0f); }
  } else {
    int e = blockIdx.x - 1024;
    if (tid == 0) cnt = 0;
    __syncthreads();
    if (tid < 128) {
      u32 w = hbitsT[e * 128 + tid];
      while (w) {
        int b = __ffs(w) - 1;
        int p = atomicAdd(&cnt, 1);
        if (p < 512) list[p] = tid * 32 + b;
        w &= w - 1;
      }
    }
    __syncthreads();
    int c = cnt < 512 ? cnt : 512;
    for (int p = tid; p < c * c; p += 256) {
      int i = list[p / c], j = list[p % c];
      atomicOr(&abits[i * 128 + (j >> 5)], 1u << (j & 31));
    }
  }
}

// masked exp rows -> fp8 expA + 1/rowsum (rowsum over fp8-rounded values)
__global__ void k_exprows(const u32* __restrict__ abits, const float* __restrict__ wh1,
                          const float* __restrict__ wh2, u8* __restrict__ expA,
                          float* rsInv) {
  int i = blockIdx.x, tid = threadIdx.x;
  __shared__ float w2s[NN];
  __shared__ float ssum;
  for (int j = tid; j < NN; j += 256) w2s[j] = wh2[j];
  if (tid == 0) ssum = 0.f;
  __syncthreads();
  float a = wh1[i], lsum = 0.f;
  #pragma unroll
  for (int it = 0; it < 4; ++it) {
    int j = it * 1024 + tid * 4;
    u32 w = abits[i * 128 + (j >> 5)];
    u32 m = (w >> (j & 31)) & 0xFu;
    float x0 = 0.f, x1 = 0.f, x2 = 0.f, x3 = 0.f;
    if (m & 1u) { float z = a + w2s[j];     float eg = z > 0.f ? z : 0.2f * z; x0 = __expf(eg); }
    if (m & 2u) { float z = a + w2s[j + 1]; float eg = z > 0.f ? z : 0.2f * z; x1 = __expf(eg); }
    if (m & 4u) { float z = a + w2s[j + 2]; float eg = z > 0.f ? z : 0.2f * z; x2 = __expf(eg); }
    if (m & 8u) { float z = a + w2s[j + 3]; float eg = z > 0.f ? z : 0.2f * z; x3 = __expf(eg); }
    u32 word = pack_fp8x4(x0, x1, x2, x3);
    *(u32*)&expA[(size_t)i * NN + j] = word;
    lsum += __builtin_amdgcn_cvt_f32_fp8(word, 0) + __builtin_amdgcn_cvt_f32_fp8(word, 1)
          + __builtin_amdgcn_cvt_f32_fp8(word, 2) + __builtin_amdgcn_cvt_f32_fp8(word, 3);
  }
  lsum = wredf(lsum);
  if ((tid & 63) == 0) atomicAdd(&ssum, lsum);
  __syncthreads();
  if (tid == 0) rsInv[i] = 1.0f / ssum;
}

__global__ void k_edge_softmax(const u16* __restrict__ g2hT, const u32* __restrict__ hbitsT,
                               const float* __restrict__ v, u16* __restrict__ att1) {
  int e = blockIdx.x, tid = threadIdx.x;
  __shared__ float evals[NN];
  __shared__ u32 hw[128];
  __shared__ float s1s, s2s; __shared__ int cs;
  if (tid == 0) { s1s = 0.f; s2s = 0.f; cs = 0; }
  if (tid < 128) hw[tid] = hbitsT[e * 128 + tid];
  __syncthreads();
  float sum1 = 0.f;
  for (int j = tid; j < NN; j += 256) {
    float ev = __expf(from_bf(g2hT[(size_t)e * NN + j]));
    evals[j] = ev; sum1 += ev;
  }
  float sum2 = 0.f; int cnt = 0;
  if (tid < 128) {
    u32 w = hw[tid]; cnt = __popc(w);
    while (w) { int b = __ffs(w) - 1; sum2 += __expf(v[tid * 32 + b]); w &= w - 1; }
  }
  sum1 = wredf(sum1); sum2 = wredf(sum2); cnt = wredi(cnt);
  if ((tid & 63) == 0) { atomicAdd(&s1s, sum1); atomicAdd(&s2s, sum2); atomicAdd(&cs, cnt); }
  __syncthreads();
  float inv1 = 1.0f / s1s;
  int c = cs;
  float inv2 = c > 0 ? 1.0f / s2s : 0.0f;
  float unif = c > 0 ? 0.0f : (1.0f / (float)NN);
  for (int j = tid; j < NN; j += 256) {
    float t = evals[j] * inv1 + unif;
    if ((hw[j >> 5] >> (j & 31)) & 1) t += __expf(v[j]) * inv2;
    att1[(size_t)e * NN + j] = to_bf(t);
  }
}

// tri: edgeT-cat GEMM (256 tiles, XCD-swizzled) | Yb GEMM | Att1->Att1T
__global__ __launch_bounds__(256, 2)
void k_tri_edge(const u16* __restrict__ Fcat, const u16* __restrict__ Att1,
                EpiEdgeT e0,
                const u16* __restrict__ X4att, const u16* __restrict__ W3b,
                EpiBf16 e1,
                const u16* __restrict__ tin, u16* __restrict__ tout) {
  __shared__ __align__(16) u16 smem[192 * 64];
  int b = blockIdx.x;
  if (b < 256) {
    const int xcd = b & 7, idx = b >> 3;          // nb=32 = 8 XCD x 4 stripes
    const int t = (idx / 4) * 32 + xcd * 4 + (idx & 3);
    gemm_body<64, 64>(Fcat, Att1, 32, NN, 0, NN, e0, t, smem, smem + 64 * 64);
  }
  else if (b < 384) gemm_body<128, 64>(X4att, W3b, 4, 256, 0, 256, e1, b - 256, smem, smem + 128 * 64);
  else { int t = b - 384; t32_tile(tin, tout, EE, NN, t & 127, t >> 7, smem); }
}

// dual2: C2 GEMM (128 tiles, K=2048) | attn2 GEMM (512 tiles)
__global__ __launch_bounds__(256, 2)
void k_dual_attn2(const u16* __restrict__ Att1T, const u16* __restrict__ Edge2T,
                  EpiF32 e0,
                  const u16* __restrict__ Yb, const u16* __restrict__ Edge,
                  EpiBf16Scale e1) {
  __shared__ __align__(16) u16 smem[256 * 64];
  int b = blockIdx.x;
  if (b < 128) gemm_body<128, 64>(Att1T, Edge2T, 4, EE, 0, EE, e0, b, smem, smem + 128 * 64);
  else         gemm_body<128, 128>(Yb, Edge, 16, 256, 0, 256, e1, b - 128, smem, smem + 128 * 64);
}

__global__ void k_node_softmax(const u16* __restrict__ g2h, const u16* __restrict__ attn2,
                               const u32* __restrict__ hbits, u16* __restrict__ att2hn) {
  int n = blockIdx.x, tid = threadIdx.x;
  __shared__ float ev3[EE], ev4[EE];
  __shared__ u32 hw[64];
  __shared__ float s3s, s4s; __shared__ int cs;
  if (tid == 0) { s3s = 0.f; s4s = 0.f; cs = 0; }
  if (tid < 64) hw[tid] = hbits[n * 64 + tid];
  __syncthreads();
  float s3 = 0.f, s4 = 0.f; int cl = 0;
  for (int e = tid; e < EE; e += 256) {
    float x3 = __expf(from_bf(g2h[(size_t)n * EE + e]));
    ev3[e] = x3; s3 += x3;
    bool m = (hw[e >> 5] >> (e & 31)) & 1;
    float x4 = m ? __expf(from_bf(attn2[(size_t)n * EE + e])) : 0.f;
    ev4[e] = x4; s4 += x4; cl += m;
  }
  s3 = wredf(s3); s4 = wredf(s4); cl = wredi(cl);
  if ((tid & 63) == 0) { atomicAdd(&s3s, s3); atomicAdd(&s4s, s4); atomicAdd(&cs, cl); }
  __syncthreads();
  float inv3 = 1.0f / s3s;
  int c = cs;
  float inv4 = c > 0 ? 1.0f / s4s : 0.0f;
  float unif = c > 0 ? 0.0f : (1.0f / (float)EE);
  for (int e = tid; e < EE; e += 256)
    att2hn[(size_t)n * EE + e] = to_bf(ev3[e] * inv3 + ev4[e] * inv4 + unif);
}

__global__ void k_transpose(const u16* __restrict__ in, u16* __restrict__ out,
                            int R, int C) {
  __shared__ u16 t[32 * 33];
  t32_tile(in, out, R, C, blockIdx.x, blockIdx.y, t);
}

__global__ void k_cast_hn2(const float* __restrict__ acc, u16* __restrict__ hn2T) {
  int idx = blockIdx.x * 256 + threadIdx.x;     // 524288
  hn2T[idx] = to_bf(acc[idx]);
}

// ---------------- launch ----------------
extern "C" void kernel_launch(void* const* d_in, const int* in_sizes, int n_in,
                              void* d_out, int out_size, void* d_ws, size_t ws_size,
                              hipStream_t stream) {
  (void)in_sizes; (void)n_in; (void)out_size; (void)ws_size;
  const float* x    = (const float*)d_in[0];
  const float* w1   = (const float*)d_in[1];
  const float* w2   = (const float*)d_in[2];
  const float* w3   = (const float*)d_in[3];
  const float* wg   = (const float*)d_in[4];
  const float* ag   = (const float*)d_in[5];
  const float* wc   = (const float*)d_in[6];
  const float* bias = (const float*)d_in[7];
  const int*   hidx = (const int*)d_in[8];
  float* out = (float*)d_out;
  char* ws = (char*)d_ws;

  u32* Hbits   = (u32*)(ws + OFF_HBITS);
  u32* HbitsT  = (u32*)(ws + OFF_HBITST);
  u32* Abits   = (u32*)(ws + OFF_ABITS);
  float* Wh1   = (float*)(ws + OFF_WH1);
  float* Wh2   = (float*)(ws + OFF_WH2);
  float* V     = (float*)(ws + OFF_V);
  float* RsInv = (float*)(ws + OFF_RSINV);
  u16* Wcat    = (u16*)(ws + OFF_WCAT);
  u16* W3b     = Wcat + 196608;
  u16* Xb      = (u16*)(ws + OFF_XB);
  u16* Whg     = (u16*)(ws + OFF_WHG);
  u16* X4att   = (u16*)(ws + OFF_X4ATT);
  u16* Yb      = (u16*)(ws + OFF_YB);
  u16* XwT     = (u16*)(ws + OFF_XWT);     // Fcat = [XwT|WhgTa] contiguous
  u16* WhgTa   = (u16*)(ws + OFF_WHGTA);
  u8*  HbT8    = (u8*)(ws + OFF_HBT);      // [HbT|WhgTb] fp8 = bigGEMM B-cat
  u8*  WhgTb8  = (u8*)(ws + OFF_WHGTB);
  u8*  ExpA8   = (u8*)(ws + OFF_EXPA);
  u16* Att1    = (u16*)(ws + OFF_ATT1);
  u16* Att1T   = (u16*)(ws + OFF_ATT1T);
  u16* Att2hn  = (u16*)(ws + OFF_ATT2HN);
  u16* G2h     = (u16*)(ws + OFF_G2H);
  u16* G2hT    = (u16*)(ws + OFF_G2HT);
  u16* Att2hnT = (u16*)(ws + OFF_ATT2HNT);
  u16* Attn2   = (u16*)(ws + OFF_ATTN2);
  float* G1    = (float*)(ws + OFF_G1);
  float* C2    = (float*)(ws + OFF_C2);
  float* Hn2Acc = (float*)(ws + OFF_HN2ACC);
  u16* Edge    = (u16*)(ws + OFF_EDGE);
  u16* EdgeT   = (u16*)(ws + OFF_EDGET);   // [EdgeT|Hn2T] = C1 B-cat contiguous
  u16* Hn2T    = (u16*)(ws + OFF_HN2T);
  u16* Edge2T  = (u16*)(ws + OFF_EDGE2T);

  // 1. casts + zeroing (bits 4 MB, HbT 8 MB fp8, Hn2Acc 2 MB)
  k_prep<<<8704, 256, 0, stream>>>(wg, w2, w1, w3, x, Wcat, Xb,
                                   ws + OFF_HBITS, ws + OFF_HBT, ws + OFF_HN2ACC);
  // 2. incidence bitsets + H^T(fp8) + A-diagonal
  k_scatter_diag<<<272, 256, 0, stream>>>(hidx, Hbits, HbitsT, HbT8, Abits);
  // 3. G0: x @ [wgT|w2T|w1T] -> Whg(+bf16 T, +fp8 T) | X4att | XwT(+bias)
  gemm_k<128, 64, 1, 3><<<384, 256, 0, stream>>>(
      Xb, Wcat, 12, 256, EpiG0{Whg, WhgTa, X4att, XwT, WhgTb8, bias});
  // 4. rowdots + clique expansion
  k_rowclique<<<3072, 256, 0, stream>>>(Whg, X4att, ag, wc, Wh1, Wh2, V,
                                        HbitsT, Abits);
  // 5. expA rows (fp8) + 1/rowsum
  k_exprows<<<NN, 256, 0, stream>>>(Abits, Wh1, Wh2, ExpA8, RsInv);
  // 6. big fused GEMM, MX-scaled fp8 K=128 (unit scales)
  gemm_mx<<<768, 256, 0, stream>>>(
      ExpA8, HbT8, 24, NN, EpiBig{RsInv, G2h, G2hT, G1});
  // 7. att1 per edge
  k_edge_softmax<<<EE, 256, 0, stream>>>(G2hT, HbitsT, V, Att1);
  // 8. tri: [EdgeT|Edge2T](+Edge) | Yb = X4att@w3^T | Att1->Att1T
  k_tri_edge<<<8576, 256, 0, stream>>>(
      XwT, Att1, EpiEdgeT{EdgeT, Edge2T, Edge},
      X4att, W3b, EpiBf16{Yb, 256},
      Att1, Att1T);
  // 9. dual2: C2 = att1^T @ edge2 | attn2 = Yb @ edge^T / temp
  k_dual_attn2<<<640, 256, 0, stream>>>(
      Att1T, Edge2T, EpiF32{C2, 256},
      Yb, Edge, EpiBf16Scale{Attn2, EE, 1.0f / 16.0f});
  // 10. att2hn per node
  k_node_softmax<<<NN, 256, 0, stream>>>(G2h, Attn2, Hbits, Att2hn);
  // 11. Att2hn -> Att2hnT
  k_transpose<<<dim3(64, 128), 256, 0, stream>>>(Att2hn, Att2hnT, NN, EE);
  // 12. hn2T = Whg^T @ att2hn: split-K4 atomics (512 blocks)
  gemm_k<64, 64, 4, 3><<<512, 256, 0, stream>>>(
      WhgTa, Att2hnT, 32, NN, EpiAtomF32{Hn2Acc, EE});
  // 13. cast Hn2Acc -> Hn2T bf16
  k_cast_hn2<<<2048, 256, 0, stream>>>(Hn2Acc, Hn2T);
  // 14. C1 = att2hn @ [edge|hn2] with fused relu/elu combine -> d_out
  gemm_k<64, 64, 1, 2><<<512, 256, 0, stream>>>(
      Att2hn, EdgeT, 8, EE, EpiCombine{G1, C2, out});
}